// Round 14
// baseline (241.204 us; speedup 1.0000x reference)
//
#include <hip/hip_runtime.h>
#include <hip/hip_bf16.h>
#include <math.h>

#define DD 512
#define NA_TOT 22904
#define NR_TOT 2904
#define MPAD_A 22960
#define MPAD_R 2960

__constant__ int c_aoff[17] = {0,1024,2145,3363,4678,6090,7599,9205,10908,12708,
                               14605,16599,17666,18830,20091,21449,22904};
__constant__ int c_roff[17] = {0,128,293,495,734,882,1067,1289,1420,1588,
                               1793,2035,2186,2374,2599,2733,2904};
__constant__ int c_apad[17] = {0,1024,2152,3376,4696,6112,7624,9232,10936,12736,
                               14640,16640,17712,18880,20144,21504,22960};
__constant__ int c_rpad[17] = {0,128,296,504,744,896,1088,1312,1448,1616,
                               1824,2072,2224,2416,2648,2784,2960};

typedef __attribute__((ext_vector_type(8))) short short8;
typedef __attribute__((ext_vector_type(4))) float f32x4;
typedef __attribute__((ext_vector_type(4))) unsigned short ushort4v;

__device__ __forceinline__ unsigned short f2bf(float f) {
  __hip_bfloat16 h = __float2bfloat16(f);   // RNE
  return *reinterpret_cast<unsigned short*>(&h);
}
__device__ __forceinline__ float bf2f(unsigned short u) {
  union { unsigned int i; float f; } c; c.i = ((unsigned int)u) << 16; return c.f;
}
__device__ __forceinline__ float wred_sum(float x){
#pragma unroll
  for (int o = 32; o > 0; o >>= 1) x += __shfl_xor(x, o, 64);
  return x;
}

// async global->LDS, 16B per lane. LDS dest = wave-uniform base + lane*16.
__device__ __forceinline__ void gl_lds16(const unsigned short* g, unsigned short* l) {
  __builtin_amdgcn_global_load_lds(
      (const __attribute__((address_space(1))) unsigned int*)g,
      (__attribute__((address_space(3))) unsigned int*)l, 16, 0, 0);
}

// ---------------- fp32 -> bf16 pre-convert (5 segments) ----------------
__global__ __launch_bounds__(256) void cvt5(
    const float* __restrict__ s0, const float* __restrict__ s1,
    const float* __restrict__ s2, const float* __restrict__ s3,
    const float* __restrict__ s4,
    unsigned short* __restrict__ d0, unsigned short* __restrict__ d1,
    unsigned short* __restrict__ d2, unsigned short* __restrict__ d3,
    unsigned short* __restrict__ d4,
    int n0, int n1, int n2, int n3, int n4)
{
  const float* s; unsigned short* d; int n;
  switch (blockIdx.y) {
    case 0: s = s0; d = d0; n = n0; break;
    case 1: s = s1; d = d1; n = n1; break;
    case 2: s = s2; d = d2; n = n2; break;
    case 3: s = s3; d = d3; n = n3; break;
    default: s = s4; d = d4; n = n4; break;
  }
  const int i = (blockIdx.x * 256 + threadIdx.x) * 4;
  if (i < n) {
    const float4 v = *reinterpret_cast<const float4*>(s + i);
    ushort4v o = { f2bf(v.x), f2bf(v.y), f2bf(v.z), f2bf(v.w) };
    *reinterpret_cast<ushort4v*>(d + i) = o;
  }
}

// ---------------- atom_node fp32 -> bf16 (8 elems/thread) ----------------
__global__ __launch_bounds__(256) void cvt_atom(const float* __restrict__ s,
                                                unsigned short* __restrict__ d, int n)
{
  const int i = (blockIdx.x * 256 + threadIdx.x) * 8;
  if (i < n) {
    const float4 v0 = *reinterpret_cast<const float4*>(s + i);
    const float4 v1 = *reinterpret_cast<const float4*>(s + i + 4);
    short8 pk;
    pk[0] = (short)f2bf(v0.x); pk[1] = (short)f2bf(v0.y);
    pk[2] = (short)f2bf(v0.z); pk[3] = (short)f2bf(v0.w);
    pk[4] = (short)f2bf(v1.x); pk[5] = (short)f2bf(v1.y);
    pk[6] = (short)f2bf(v1.z); pk[7] = (short)f2bf(v1.w);
    *reinterpret_cast<short8*>(d + i) = pk;
  }
}

// ---------------- padded-row -> source-row maps ----------------
__global__ __launch_bounds__(256) void mkmap(int* __restrict__ mapA,
                                             int* __restrict__ mapR)
{
  const int pm = blockIdx.x * 256 + threadIdx.x;
  if (pm < MPAD_A) {
    int b = 0;
#pragma unroll
    for (int i = 1; i < 16; ++i) if (pm >= c_apad[i]) b = i;
    const int rel = pm - c_apad[b];
    const int L = c_aoff[b+1] - c_aoff[b];
    mapA[pm] = c_aoff[b] + min(rel, L - 1);
  }
  if (pm < MPAD_R) {
    int b = 0;
#pragma unroll
    for (int i = 1; i < 16; ++i) if (pm >= c_rpad[i]) b = i;
    const int rel = pm - c_rpad[b];
    const int L = c_roff[b+1] - c_roff[b];
    mapR[pm] = c_roff[b] + min(rel, L - 1);
  }
}

// ---------- combined weights: Wc = A @ Wo (fp32 in, bf16 out) ----------
// z=0: A=Wk2 -> Ck ; z=1: A=Wv2 -> Cv. 32x32 tiles, grid (16,16,2).
__global__ __launch_bounds__(256) void wcomb(const float* __restrict__ a2r_in_w,
                                             const float* __restrict__ Wo,
                                             unsigned short* __restrict__ Ck,
                                             unsigned short* __restrict__ Cv)
{
  __shared__ float As[32][36];
  __shared__ float Bs[32][36];
  const float* A = a2r_in_w + (blockIdx.z ? 524288 : 262144);
  unsigned short* C = blockIdx.z ? Cv : Ck;
  const int m0 = blockIdx.x * 32, n0 = blockIdx.y * 32;
  const int tid = threadIdx.x;
  const int ty = tid >> 4, tx = tid & 15;
  const int lr = tid >> 3, lc = (tid & 7) * 4;
  float acc[2][2] = {{0.f,0.f},{0.f,0.f}};
  for (int kb = 0; kb < 512; kb += 32) {
    const float4 av = *reinterpret_cast<const float4*>(A + (size_t)(m0+lr)*512 + kb + lc);
    As[lr][lc+0]=av.x; As[lr][lc+1]=av.y; As[lr][lc+2]=av.z; As[lr][lc+3]=av.w;
    const float4 bv = *reinterpret_cast<const float4*>(Wo + (size_t)(kb+lr)*512 + n0 + lc);
    Bs[lr][lc+0]=bv.x; Bs[lr][lc+1]=bv.y; Bs[lr][lc+2]=bv.z; Bs[lr][lc+3]=bv.w;
    __syncthreads();
#pragma unroll
    for (int k = 0; k < 32; ++k) {
      const float a0 = As[ty*2][k],   a1 = As[ty*2+1][k];
      const float b0 = Bs[k][tx*2],   b1 = Bs[k][tx*2+1];
      acc[0][0] = fmaf(a0,b0,acc[0][0]); acc[0][1] = fmaf(a0,b1,acc[0][1]);
      acc[1][0] = fmaf(a1,b0,acc[1][0]); acc[1][1] = fmaf(a1,b1,acc[1][1]);
    }
    __syncthreads();
  }
#pragma unroll
  for (int i = 0; i < 2; ++i)
#pragma unroll
    for (int j = 0; j < 2; ++j)
      C[(size_t)(m0+ty*2+i)*512 + n0 + tx*2+j] = f2bf(acc[i][j]);
}

// ---------- combined biases: bc = A @ bo + b2 (fp32) ----------
__global__ __launch_bounds__(256) void bcomb(const float* __restrict__ a2r_in_w,
                                             const float* __restrict__ bo,
                                             const float* __restrict__ a2r_in_b,
                                             float* __restrict__ bck,
                                             float* __restrict__ bcv)
{
  const int n = blockIdx.x * 256 + threadIdx.x;    // grid.x = 2 -> n in [0,512)
  const float* A  = a2r_in_w + (blockIdx.y ? 524288 : 262144) + (size_t)n * 512;
  const float* b2 = a2r_in_b + (blockIdx.y ? 1024 : 512);
  float s = 0.f;
  for (int j = 0; j < 512; j += 4) {
    const float4 w = *reinterpret_cast<const float4*>(A + j);
    const float4 b = *reinterpret_cast<const float4*>(bo + j);
    s = fmaf(w.x,b.x,s); s = fmaf(w.y,b.y,s); s = fmaf(w.z,b.z,s); s = fmaf(w.w,b.w,s);
  }
  (blockIdx.y ? bcv : bck)[n] = s + b2[n];
}

// ============ Multi-segment MFMA GEMM (counted-vmcnt, X depth-2 pipeline) =====
struct GSeg {
  const void* X; const unsigned short* W; const float* bias;
  unsigned short* Y; const int* map;
  int M; int ldY; int mtiles; int flags;   // flags: 2=transposed store, 4=remap
};
struct GSeg4 { GSeg s[4]; };

__global__ __launch_bounds__(256) void gemm_multi(GSeg4 P, int mtpx)
{
  __shared__ unsigned short SMEM[40960];   // X0|X1|X2|W0|W1 (80KB)
  unsigned short* const Xb0 = SMEM;
  unsigned short* const Xb1 = SMEM + 8192;
  unsigned short* const Xb2 = SMEM + 16384;
  unsigned short* const Wb0 = SMEM + 24576;
  unsigned short* const Wb1 = SMEM + 32768;
  const GSeg sg = P.s[blockIdx.y];
  const int xcd = blockIdx.x & 7, g = blockIdx.x >> 3;
  const int mt = xcd + 8 * (g % mtpx);
  const int nt = g / mtpx;
  if (mt >= sg.mtiles) return;
  const int m0 = mt * 128, n0 = nt * 128;
  const int OUTT = sg.flags & 2, REMAP = sg.flags & 4;
  const int tid = threadIdx.x, lane = tid & 63, w = tid >> 6;
  const int la = lane & 15, lg = lane >> 4;
  const int wm = (w & 1) * 64, wn = (w >> 1) * 64;
  const int w64 = w * 64;
  const unsigned short* Xg = (const unsigned short*)sg.X;

  f32x4 acc[4][4];
#pragma unroll
  for (int i = 0; i < 4; ++i)
#pragma unroll
    for (int j = 0; j < 4; ++j) acc[i][j] = (f32x4){0.f,0.f,0.f,0.f};

  int elA[4][2], elB[4][2];
#pragma unroll
  for (int i = 0; i < 4; ++i)
#pragma unroll
    for (int kc = 0; kc < 2; ++kc) {
      { const int r = wm + i*16 + la;
        elA[i][kc] = r*64 + ((kc*32 + lg*8) ^ ((r & 7) << 3)); }
      { const int r = wn + i*16 + la;
        elB[i][kc] = r*64 + ((kc*32 + lg*8) ^ ((r & 7) << 3)); }
    }

  int srow[4];
#pragma unroll
  for (int p = 0; p < 4; ++p) {
    const int slot = p*256 + tid;
    const int rg = min(m0 + (slot >> 3), sg.M - 1);
    srow[p] = REMAP ? sg.map[rg] : rg;
  }
  int scg[4], srw[4];
#pragma unroll
  for (int p = 0; p < 4; ++p) {
    const int slot = p*256 + tid;
    srw[p] = slot >> 3;
    scg[p] = ((slot & 7) ^ (srw[p] & 7)) << 3;   // swizzled GLOBAL col; LDS linear
  }

#define STAGE_W(DST, kb_)                                                       \
  _Pragma("unroll")                                                             \
  for (int p = 0; p < 4; ++p)                                                   \
    gl_lds16(sg.W + (size_t)(n0 + srw[p]) * DD + (kb_) + scg[p],                \
             &(DST)[(p*256 + w64) * 8]);

#define STAGE_X(DST, kb_)                                                       \
  _Pragma("unroll")                                                             \
  for (int p = 0; p < 4; ++p)                                                   \
    gl_lds16(Xg + (size_t)srow[p] * DD + (kb_) + scg[p],                        \
             &(DST)[(p*256 + w64) * 8]);

#define COMPUTE(XB, WB)                                                         \
  {                                                                             \
    short8 af[4][2], bfm[4][2];                                                 \
    _Pragma("unroll")                                                           \
    for (int i = 0; i < 4; ++i)                                                 \
      _Pragma("unroll")                                                         \
      for (int kc = 0; kc < 2; ++kc) {                                          \
        af[i][kc]  = *reinterpret_cast<const short8*>(&(XB)[elA[i][kc]]);       \
        bfm[i][kc] = *reinterpret_cast<const short8*>(&(WB)[elB[i][kc]]);       \
      }                                                                         \
    _Pragma("unroll")                                                           \
    for (int kc = 0; kc < 2; ++kc)                                              \
      _Pragma("unroll")                                                         \
      for (int i = 0; i < 4; ++i)                                               \
        _Pragma("unroll")                                                       \
        for (int j = 0; j < 4; ++j)                                             \
          acc[i][j] = __builtin_amdgcn_mfma_f32_16x16x32_bf16(af[i][kc], bfm[j][kc], acc[i][j], 0, 0, 0); \
  }

  STAGE_W(Wb0, 0);
  STAGE_X(Xb0, 0);
  STAGE_X(Xb1, 64);

#pragma unroll
  for (int k = 0; k < 8; ++k) {
    __builtin_amdgcn_s_barrier();
    asm volatile("" ::: "memory");
    if (k + 1 < 8) {
      if (((k+1) & 1) == 0) { STAGE_W(Wb0, (k+1)*64); } else { STAGE_W(Wb1, (k+1)*64); }
    }
    if (k + 2 < 8) {
      if (((k+2) % 3) == 0) { STAGE_X(Xb0, (k+2)*64); }
      else if (((k+2) % 3) == 1) { STAGE_X(Xb1, (k+2)*64); }
      else { STAGE_X(Xb2, (k+2)*64); }
    }
    if (k < 6)       { asm volatile("s_waitcnt vmcnt(12)" ::: "memory"); }
    else if (k == 6) { asm volatile("s_waitcnt vmcnt(8)" ::: "memory"); }
    else             { asm volatile("s_waitcnt vmcnt(0)" ::: "memory"); }
    __builtin_amdgcn_s_barrier();
    asm volatile("" ::: "memory");
    __builtin_amdgcn_sched_barrier(0);
    if ((k % 3) == 0)      { if ((k & 1) == 0) COMPUTE(Xb0, Wb0) else COMPUTE(Xb0, Wb1) }
    else if ((k % 3) == 1) { if ((k & 1) == 0) COMPUTE(Xb1, Wb0) else COMPUTE(Xb1, Wb1) }
    else                   { if ((k & 1) == 0) COMPUTE(Xb2, Wb0) else COMPUTE(Xb2, Wb1) }
  }

#undef STAGE_W
#undef STAGE_X
#undef COMPUTE

  __syncthreads();
  unsigned short* Cs = SMEM;
  if (!OUTT) {
#pragma unroll
    for (int j = 0; j < 4; ++j) {
      const int n = wn + j*16 + la;
      const float bj = sg.bias[n0 + n];
#pragma unroll
      for (int i = 0; i < 4; ++i) {
        const int mb = wm + i*16 + lg*4;
#pragma unroll
        for (int r = 0; r < 4; ++r) {
          const int m = mb + r;
          Cs[m*128 + (((n >> 3) ^ (m & 7)) << 3) + (n & 7)] = f2bf(acc[i][j][r] + bj);
        }
      }
    }
    __syncthreads();
#pragma unroll
    for (int p = 0; p < 8; ++p) {
      const int sid = p*256 + tid;
      const int row = sid >> 4, s = sid & 15;
      if (m0 + row < sg.M) {
        const short8 v = *reinterpret_cast<const short8*>(&Cs[row*128 + ((s ^ (row & 7)) << 3)]);
        *reinterpret_cast<short8*>(sg.Y + (size_t)(m0 + row)*sg.ldY + n0 + s*8) = v;
      }
    }
  } else {
#pragma unroll
    for (int j = 0; j < 4; ++j) {
      const int n = wn + j*16 + la;
      const float bj = sg.bias[n0 + n];
#pragma unroll
      for (int i = 0; i < 4; ++i) {
        const int mb = wm + i*16 + lg*4;
#pragma unroll
        for (int r = 0; r < 4; ++r) {
          const int m = mb + r;
          Cs[n*128 + (((m >> 3) ^ (n & 7)) << 3) + (m & 7)] = f2bf(acc[i][j][r] + bj);
        }
      }
    }
    __syncthreads();
#pragma unroll
    for (int p = 0; p < 8; ++p) {
      const int sid = p*256 + tid;
      const int row = sid >> 4, s = sid & 15;
      if (m0 + s*8 < sg.M) {
        const short8 v = *reinterpret_cast<const short8*>(&Cs[row*128 + ((s ^ (row & 7)) << 3)]);
        *reinterpret_cast<short8*>(sg.Y + (size_t)(n0 + row)*sg.ldY + m0 + s*8) = v;
      }
    }
  }
}

// ====== attention STAGE/COMPUTE macros (shared by attn_v7 / attn_sk) ==========
#define ATT_STAGE(bi, kc_)                                                      \
  {                                                                             \
    const int kbase_ = (kc_) * 64;                                              \
    _Pragma("unroll")                                                           \
    for (int p = 0; p < 2; ++p) {                                               \
      const int slot = p*256 + tid;                                             \
      const int row = slot >> 3, cg = slot & 7;                                 \
      const int srow = min(kbase_ + row, padL - 1);                             \
      gl_lds16(Kb + (size_t)srow * DD + ((cg ^ (row & 7)) << 3),                \
               &Ks[bi][(p*256 + w*64) * 8]);                                    \
    }                                                                           \
    _Pragma("unroll")                                                           \
    for (int p = 0; p < 2; ++p) {                                               \
      const int slot = p*256 + tid;                                             \
      const int row = slot >> 3, cg = slot & 7;                                 \
      const int col = min(kbase_ + ((cg ^ (row & 7)) << 3), padL - 8);          \
      gl_lds16(VTb + (size_t)row * ldvt + col, &Vs[bi][(p*256 + w*64) * 8]);    \
    }                                                                           \
  }

#define ATT_COMPUTE(bi, kbase)                                                  \
  {                                                                             \
    f32x4 S[4];                                                                 \
    _Pragma("unroll")                                                           \
    for (int j = 0; j < 4; ++j) {                                               \
      const int row = j*16 + la;                                                \
      const short8 kf0 = *reinterpret_cast<const short8*>(                      \
          &Ks[bi][row*64 + ((lg*8) ^ ((row & 7) << 3))]);                       \
      const short8 kf1 = *reinterpret_cast<const short8*>(                      \
          &Ks[bi][row*64 + ((32 + lg*8) ^ ((row & 7) << 3))]);                  \
      f32x4 s = (f32x4){0.f,0.f,0.f,0.f};                                       \
      s = __builtin_amdgcn_mfma_f32_16x16x32_bf16(qf[0], kf0, s, 0, 0, 0);      \
      s = __builtin_amdgcn_mfma_f32_16x16x32_bf16(qf[1], kf1, s, 0, 0, 0);      \
      S[j] = s;                                                                 \
    }                                                                           \
    _Pragma("unroll")                                                           \
    for (int j = 0; j < 4; ++j) {                                               \
      const bool ok = (kbase + j*16 + la) < Lk;                                 \
      _Pragma("unroll")                                                         \
      for (int r = 0; r < 4; ++r) {                                             \
        const float p = ok ? __expf(S[j][r] * 0.125f) : 0.f;                    \
        S[j][r] = p;                                                            \
        lsum[r] += p;                                                           \
      }                                                                         \
    }                                                                           \
    _Pragma("unroll")                                                           \
    for (int r = 0; r < 4; ++r) {                                               \
      const int prow = lg*4 + r;                                                \
      _Pragma("unroll")                                                         \
      for (int j = 0; j < 4; ++j)                                               \
        Pl[w][prow*64 + ((j*16 + la) ^ ((prow & 7) << 3))] = f2bf(S[j][r]);     \
    }                                                                           \
    __builtin_amdgcn_wave_barrier();                                            \
    const short8 pf0 = *reinterpret_cast<const short8*>(                        \
        &Pl[w][la*64 + ((lg*8) ^ ((la & 7) << 3))]);                            \
    const short8 pf1 = *reinterpret_cast<const short8*>(                        \
        &Pl[w][la*64 + ((32 + lg*8) ^ ((la & 7) << 3))]);                       \
    _Pragma("unroll")                                                           \
    for (int j = 0; j < 4; ++j) {                                               \
      const int d = j*16 + la;                                                  \
      const short8 vf0 = *reinterpret_cast<const short8*>(                      \
          &Vs[bi][d*64 + ((lg*8) ^ ((d & 7) << 3))]);                           \
      const short8 vf1 = *reinterpret_cast<const short8*>(                      \
          &Vs[bi][d*64 + ((32 + lg*8) ^ ((d & 7) << 3))]);                      \
      acc[j] = __builtin_amdgcn_mfma_f32_16x16x32_bf16(pf0, vf0, acc[j], 0, 0, 0); \
      acc[j] = __builtin_amdgcn_mfma_f32_16x16x32_bf16(pf1, vf1, acc[j], 0, 0, 0); \
    }                                                                           \
  }

// ============== attn1: full attention, counted-vmcnt staging ==================
__global__ __launch_bounds__(256, 4) void attn_v7(const unsigned short* __restrict__ Q,
                                                  const unsigned short* __restrict__ K,
                                                  const unsigned short* __restrict__ VT,
                                                  unsigned short* __restrict__ O, int ldvt)
{
  __shared__ unsigned short Ks[2][64*64];
  __shared__ unsigned short Vs[2][64*64];
  __shared__ unsigned short Pl[4][16*64];
  const int b = blockIdx.x >> 3, h = blockIdx.x & 7;
  const int Lq = c_aoff[b+1]-c_aoff[b], Lk = c_roff[b+1]-c_roff[b];
  const int padL = c_rpad[b+1]-c_rpad[b];
  const int q0b = blockIdx.y * 64;
  if (q0b >= Lq) return;
  const int tid = threadIdx.x, w = tid >> 6, lane = tid & 63;
  const int la = lane & 15, lg = lane >> 4;
  const int q0 = q0b + w*16;
  const unsigned short* Qb  = Q  + (size_t)c_aoff[b]*DD + h*64;
  const unsigned short* Kb  = K  + (size_t)c_rpad[b]*DD + h*64;
  const unsigned short* VTb = VT + (size_t)(h*64)*ldvt + c_rpad[b];

  short8 qf[2];
  {
    const int qrow = min(q0 + la, Lq - 1);
    qf[0] = *reinterpret_cast<const short8*>(Qb + (size_t)qrow*DD + lg*8);
    qf[1] = *reinterpret_cast<const short8*>(Qb + (size_t)qrow*DD + 32 + lg*8);
  }

  f32x4 acc[4];
#pragma unroll
  for (int j = 0; j < 4; ++j) acc[j] = (f32x4){0.f,0.f,0.f,0.f};
  float lsum[4] = {0.f,0.f,0.f,0.f};

  const int nkc = (Lk + 63) >> 6;
  ATT_STAGE(0, 0);
  for (int kc = 0; kc < nkc; ++kc) {
    const int bi = kc & 1;
    __builtin_amdgcn_s_barrier();
    asm volatile("" ::: "memory");
    if (kc + 1 < nkc) {
      ATT_STAGE(bi ^ 1, kc + 1);
      asm volatile("s_waitcnt vmcnt(4)" ::: "memory");
    } else {
      asm volatile("s_waitcnt vmcnt(0)" ::: "memory");
    }
    __builtin_amdgcn_s_barrier();
    asm volatile("" ::: "memory");
    __builtin_amdgcn_sched_barrier(0);
    const int kbase = kc * 64;
    ATT_COMPUTE(bi, kbase);
  }

#pragma unroll
  for (int msk = 1; msk <= 8; msk <<= 1)
#pragma unroll
    for (int r = 0; r < 4; ++r) lsum[r] += __shfl_xor(lsum[r], msk, 64);

#pragma unroll
  for (int r = 0; r < 4; ++r) {
    const float inv = 1.f / lsum[r];
    const int prow = lg*4 + r;
#pragma unroll
    for (int j = 0; j < 4; ++j)
      Pl[w][prow*64 + ((j*16 + la) ^ ((prow & 7) << 3))] = f2bf(acc[j][r] * inv);
  }
  __builtin_amdgcn_wave_barrier();
#pragma unroll
  for (int p = 0; p < 2; ++p) {
    const int sid = p*64 + lane;
    const int row = sid >> 3, s = sid & 7;
    const int qrow = q0 + row;
    if (qrow < Lq) {
      const short8 v = *reinterpret_cast<const short8*>(
          &Pl[w][row*64 + ((s ^ (row & 7)) << 3)]);
      *reinterpret_cast<short8*>(O + (size_t)(c_aoff[b] + qrow)*DD + h*64 + s*8) = v;
    }
  }
}

// ============== attn2: split-K partial attention (q=res, k/v=atoms) ===========
__global__ __launch_bounds__(256, 4) void attn_sk(const unsigned short* __restrict__ Q,
                                                  const unsigned short* __restrict__ K,
                                                  const unsigned short* __restrict__ VT,
                                                  float* __restrict__ Pout)
{
  __shared__ unsigned short Ks[2][64*64];
  __shared__ unsigned short Vs[2][64*64];
  __shared__ unsigned short Pl[4][16*64];
  const int b = blockIdx.x >> 3, h = blockIdx.x & 7;
  const int qt = blockIdx.y, z = blockIdx.z;
  const int Lq = c_roff[b+1]-c_roff[b], Lk = c_aoff[b+1]-c_aoff[b];
  const int padL = c_apad[b+1]-c_apad[b];
  const int ldvt = MPAD_A;
  const int q0b = qt * 64;
  if (q0b >= Lq) return;
  const int tid = threadIdx.x, w = tid >> 6, lane = tid & 63;
  const int la = lane & 15, lg = lane >> 4;
  const int q0 = q0b + w*16;
  float* pp = Pout + ((size_t)(blockIdx.x*4 + qt)*4 + z) * 4160;

  const int nkc = (Lk + 63) >> 6;
  const int cps = (nkc + 3) >> 2;
  const int k0 = z * cps, k1 = min(k0 + cps, nkc);
  if (k0 >= k1) {
    for (int i = tid; i < 4160; i += 256) pp[i] = 0.f;
    return;
  }

  const unsigned short* Qb  = Q  + (size_t)c_roff[b]*DD + h*64;
  const unsigned short* Kb  = K  + (size_t)c_apad[b]*DD + h*64;
  const unsigned short* VTb = VT + (size_t)(h*64)*ldvt + c_apad[b];

  short8 qf[2];
  {
    const int qrow = min(q0 + la, Lq - 1);
    qf[0] = *reinterpret_cast<const short8*>(Qb + (size_t)qrow*DD + lg*8);
    qf[1] = *reinterpret_cast<const short8*>(Qb + (size_t)qrow*DD + 32 + lg*8);
  }

  f32x4 acc[4];
#pragma unroll
  for (int j = 0; j < 4; ++j) acc[j] = (f32x4){0.f,0.f,0.f,0.f};
  float lsum[4] = {0.f,0.f,0.f,0.f};

  ATT_STAGE(0, k0);
  for (int kc = k0; kc < k1; ++kc) {
    const int bi = (kc - k0) & 1;
    __builtin_amdgcn_s_barrier();
    asm volatile("" ::: "memory");
    if (kc + 1 < k1) {
      ATT_STAGE(bi ^ 1, kc + 1);
      asm volatile("s_waitcnt vmcnt(4)" ::: "memory");
    } else {
      asm volatile("s_waitcnt vmcnt(0)" ::: "memory");
    }
    __builtin_amdgcn_s_barrier();
    asm volatile("" ::: "memory");
    __builtin_amdgcn_sched_barrier(0);
    const int kbase = kc * 64;
    ATT_COMPUTE(bi, kbase);
  }

#pragma unroll
  for (int msk = 1; msk <= 8; msk <<= 1)
#pragma unroll
    for (int r = 0; r < 4; ++r) lsum[r] += __shfl_xor(lsum[r], msk, 64);

#pragma unroll
  for (int j = 0; j < 4; ++j)
#pragma unroll
    for (int r = 0; r < 4; ++r)
      pp[(size_t)(w*16 + lg*4 + r)*64 + j*16 + la] = acc[j][r];
  if (la == 0) {
#pragma unroll
    for (int r = 0; r < 4; ++r) pp[4096 + w*16 + lg*4 + r] = lsum[r];
  }
}

// ============== attn2 reduce: sum 4 splits, normalize, write O2 bf16 ==========
__global__ __launch_bounds__(256) void attn_red(const float* __restrict__ Pin,
                                                unsigned short* __restrict__ O)
{
  const int b = blockIdx.x >> 3;
  const int h = blockIdx.x & 7;
  const int qt = blockIdx.y;
  const int Lq = c_roff[b+1]-c_roff[b];
  const int q0b = qt * 64;
  if (q0b >= Lq) return;
  const int t = threadIdx.x;
  const int row = t >> 2, dg = (t & 3) * 16;
  if (q0b + row >= Lq) return;
  const float* base = Pin + ((size_t)(blockIdx.x*4 + qt)*4) * 4160;
  const float ls = base[4096 + row] + base[4160 + 4096 + row]
                 + base[2*4160 + 4096 + row] + base[3*4160 + 4096 + row];
  const float inv = 1.f / ls;
  unsigned short ov[16];
#pragma unroll
  for (int e = 0; e < 16; ++e) {
    const int idx = row*64 + dg + e;
    const float s = base[idx] + base[4160 + idx] + base[2*4160 + idx] + base[3*4160 + idx];
    ov[e] = f2bf(s * inv);
  }
  unsigned short* dst = O + (size_t)(c_roff[b] + q0b + row)*DD + h*64 + dg;
  *reinterpret_cast<short8*>(dst)     = *reinterpret_cast<short8*>(&ov[0]);
  *reinterpret_cast<short8*>(dst + 8) = *reinterpret_cast<short8*>(&ov[8]);
}

// -------- LayerNorm over bf16 upd + fp32 residual -> fp32 d_out --------
__global__ __launch_bounds__(256) void ln_res(const unsigned short* __restrict__ Ub,
    float* __restrict__ Yout,
    const float* __restrict__ atom_node, const float* __restrict__ res_node,
    const float* __restrict__ ag, const float* __restrict__ ab,
    const float* __restrict__ rg, const float* __restrict__ rb)
{
  const int row = blockIdx.x * 4 + (threadIdx.x >> 6);
  const int lane = threadIdx.x & 63;
  if (row >= NA_TOT + NR_TOT) return;
  const float* g; const float* bb; const float* resid;
  if (row < NA_TOT) { g = ag; bb = ab; resid = atom_node + (size_t)row * DD; }
  else { g = rg; bb = rb; resid = res_node + (size_t)(row - NA_TOT) * DD; }
  const short8 xb = *reinterpret_cast<const short8*>(Ub + (size_t)row*DD + lane*8);
  float xv[8];
#pragma unroll
  for (int i = 0; i < 8; ++i) xv[i] = bf2f((unsigned short)xb[i]);
  float s = 0.f;
#pragma unroll
  for (int i = 0; i < 8; ++i) s += xv[i];
  s = wred_sum(s);
  const float mean = s * (1.f/512.f);
  float vs = 0.f;
#pragma unroll
  for (int i = 0; i < 8; ++i) { const float d = xv[i] - mean; vs = fmaf(d, d, vs); }
  vs = wred_sum(vs) * (1.f/512.f);
  const float inv = rsqrtf(vs + 1e-5f);
  const float4 g0 = *reinterpret_cast<const float4*>(g + lane*8);
  const float4 g1 = *reinterpret_cast<const float4*>(g + lane*8 + 4);
  const float4 b0 = *reinterpret_cast<const float4*>(bb + lane*8);
  const float4 b1 = *reinterpret_cast<const float4*>(bb + lane*8 + 4);
  const float4 r0 = *reinterpret_cast<const float4*>(resid + lane*8);
  const float4 r1 = *reinterpret_cast<const float4*>(resid + lane*8 + 4);
  float4 o0, o1;
  o0.x = (xv[0]-mean)*inv*g0.x + b0.x + r0.x;
  o0.y = (xv[1]-mean)*inv*g0.y + b0.y + r0.y;
  o0.z = (xv[2]-mean)*inv*g0.z + b0.z + r0.z;
  o0.w = (xv[3]-mean)*inv*g0.w + b0.w + r0.w;
  o1.x = (xv[4]-mean)*inv*g1.x + b1.x + r1.x;
  o1.y = (xv[5]-mean)*inv*g1.y + b1.y + r1.y;
  o1.z = (xv[6]-mean)*inv*g1.z + b1.z + r1.z;
  o1.w = (xv[7]-mean)*inv*g1.w + b1.w + r1.w;
  float* y = Yout + (size_t)row * DD + lane*8;
  *reinterpret_cast<float4*>(y)     = o0;
  *reinterpret_cast<float4*>(y + 4) = o1;
}

extern "C" void kernel_launch(void* const* d_in, const int* in_sizes, int n_in,
                              void* d_out, int out_size, void* d_ws, size_t ws_size,
                              hipStream_t stream) {
  (void)in_sizes; (void)n_in; (void)out_size; (void)ws_size;
  const float* atom_node = (const float*)d_in[0];
  const float* res_node  = (const float*)d_in[1];
  const float* r2a_in_w  = (const float*)d_in[2];
  const float* r2a_in_b  = (const float*)d_in[3];
  const float* r2a_out_w = (const float*)d_in[4];
  const float* r2a_out_b = (const float*)d_in[5];
  const float* a2r_in_w  = (const float*)d_in[6];
  const float* a2r_in_b  = (const float*)d_in[7];
  const float* a2r_out_w = (const float*)d_in[8];
  const float* a2r_out_b = (const float*)d_in[9];
  const float* atom_ln_g = (const float*)d_in[10];
  const float* atom_ln_b = (const float*)d_in[11];
  const float* res_ln_g  = (const float*)d_in[12];
  const float* res_ln_b  = (const float*)d_in[13];

  float* out = (float*)d_out;
  unsigned short* wsb = (unsigned short*)d_ws;
  const size_t NAD = (size_t)NA_TOT * DD;
  const size_t NRD = (size_t)NR_TOT * DD;
  const size_t PAD = (size_t)MPAD_A * DD;
  const size_t PRD = (size_t)MPAD_R * DD;
  // ws layout (~151 MB of 256 MB):
  unsigned short* slab1  = wsb;                    // [PAD] Q1 -> K2
  unsigned short* slab2  = wsb + PAD;              // [PAD] atom_bf -> O1
  unsigned short* slab3  = wsb + 2*PAD;            // [PAD] V2T
  unsigned short* updb   = wsb + 3*PAD;            // [NAD+NRD]
  unsigned short* res_bf = updb + NAD + NRD;       // [NRD]
  unsigned short* K1     = res_bf + NRD;           // [PRD]
  unsigned short* V1T    = K1 + PRD;               // [PRD]
  unsigned short* Q2     = V1T + PRD;              // [NRD]
  unsigned short* O2     = Q2 + NRD;               // [NRD]
  unsigned short* wbf    = O2 + NRD;               // [2097152]
  unsigned short* w_r2a_in  = wbf;
  unsigned short* w_r2a_out = wbf +  786432;
  unsigned short* w_a2r_in  = wbf + 1048576;
  unsigned short* w_a2r_out = wbf + 1835008;
  int* mapA = (int*)(wbf + 2097152);               // [MPAD_A]
  int* mapR = mapA + MPAD_A;                       // [MPAD_R]
  unsigned short* wc_k = (unsigned short*)(mapR + MPAD_R);   // [262144]
  unsigned short* wc_v = wc_k + 262144;                      // [262144]
  float* bc_k = (float*)(wc_v + 262144);           // [512]
  float* bc_v = bc_k + 512;                        // [512]
  float* partials = (float*)(bc_v + 512);          // [512*4*4160 fp32]
  unsigned short* Q1      = slab1;
  unsigned short* atom_bf = slab2;
  unsigned short* O1      = slab2;
  unsigned short* K2      = slab1;
  unsigned short* V2T     = slab3;

  const dim3 blk(256);

  // ---- prep: maps, bf16 converts, combined weights/biases ----
  mkmap<<<dim3((MPAD_A + 255)/256), blk, 0, stream>>>(mapA, mapR);
  cvt5<<<dim3(1452, 5), blk, 0, stream>>>(
      r2a_in_w, r2a_out_w, a2r_in_w, a2r_out_w, res_node,
      w_r2a_in, w_r2a_out, w_a2r_in, w_a2r_out, res_bf,
      786432, 262144, 786432, 262144, (int)NRD);
  cvt_atom<<<dim3((int)(NAD/2048)), blk, 0, stream>>>(atom_node, atom_bf, (int)NAD);
  wcomb<<<dim3(16, 16, 2), blk, 0, stream>>>(a2r_in_w, r2a_out_w, wc_k, wc_v);
  bcomb<<<dim3(2, 2), blk, 0, stream>>>(a2r_in_w, r2a_out_b, a2r_in_b, bc_k, bc_v);

  // ---- group A: Q1, K1, V1T, Q2 projections (one launch)
  {
    GSeg4 A;
    A.s[0] = { atom_bf, w_r2a_in,          r2a_in_b,        Q1,  nullptr, NA_TOT, 512,    179, 0 };
    A.s[1] = { res_bf,  w_r2a_in + 262144, r2a_in_b + 512,  K1,  mapR,    MPAD_R, 512,    24,  4 };
    A.s[2] = { res_bf,  w_r2a_in + 524288, r2a_in_b + 1024, V1T, mapR,    MPAD_R, MPAD_R, 24,  6 };
    A.s[3] = { res_bf,  w_a2r_in,          a2r_in_b,        Q2,  nullptr, NR_TOT, 512,    23,  0 };
    gemm_multi<<<dim3(736, 4), blk, 0, stream>>>(A, 23);
  }
  // ---- attention 1 (q=atoms, k/v=res)
  attn_v7<<<dim3(128, 32), blk, 0, stream>>>(Q1, K1, V1T, O1, MPAD_R);
  // ---- group B': updb, K2, V2T — all directly from O1 (combined weights)
  {
    GSeg4 B;
    B.s[0] = { O1, w_r2a_out, r2a_out_b, updb, nullptr, NA_TOT, 512,    179, 0 };
    B.s[1] = { O1, wc_k,      bc_k,      K2,   mapA,    MPAD_A, 512,    180, 4 };
    B.s[2] = { O1, wc_v,      bc_v,      V2T,  mapA,    MPAD_A, MPAD_A, 180, 6 };
    B.s[3] = B.s[0];
    gemm_multi<<<dim3(736, 3), blk, 0, stream>>>(B, 23);
  }
  // ---- attention 2: split-K partials + reduce
  attn_sk<<<dim3(128, 4, 4), blk, 0, stream>>>(Q2, K2, V2T, partials);
  attn_red<<<dim3(128, 4), blk, 0, stream>>>(partials, O2);
  // ---- out-proj 2
  {
    GSeg4 E;
    E.s[0] = { O2, w_a2r_out, a2r_out_b, updb + NAD, nullptr, NR_TOT, 512, 23, 0 };
    E.s[1] = E.s[0]; E.s[2] = E.s[0]; E.s[3] = E.s[0];
    gemm_multi<<<dim3(96, 1), blk, 0, stream>>>(E, 3);
  }
  // ---- LayerNorm + residual
  ln_res<<<dim3((NA_TOT + NR_TOT + 3) / 4), blk, 0, stream>>>(
      updb, out, atom_node, res_node, atom_ln_g, atom_ln_b, res_ln_g, res_ln_b);
}

// Round 15
// 240.561 us; speedup vs baseline: 1.0027x; 1.0027x over previous
//
#include <hip/hip_runtime.h>
#include <hip/hip_bf16.h>
#include <math.h>

#define DD 512
#define NA_TOT 22904
#define NR_TOT 2904
#define MPAD_A 22960
#define MPAD_R 2960

__constant__ int c_aoff[17] = {0,1024,2145,3363,4678,6090,7599,9205,10908,12708,
                               14605,16599,17666,18830,20091,21449,22904};
__constant__ int c_roff[17] = {0,128,293,495,734,882,1067,1289,1420,1588,
                               1793,2035,2186,2374,2599,2733,2904};
__constant__ int c_apad[17] = {0,1024,2152,3376,4696,6112,7624,9232,10936,12736,
                               14640,16640,17712,18880,20144,21504,22960};
__constant__ int c_rpad[17] = {0,128,296,504,744,896,1088,1312,1448,1616,
                               1824,2072,2224,2416,2648,2784,2960};

typedef __attribute__((ext_vector_type(8))) short short8;
typedef __attribute__((ext_vector_type(4))) float f32x4;
typedef __attribute__((ext_vector_type(4))) unsigned short ushort4v;

__device__ __forceinline__ unsigned short f2bf(float f) {
  __hip_bfloat16 h = __float2bfloat16(f);   // RNE
  return *reinterpret_cast<unsigned short*>(&h);
}
__device__ __forceinline__ float bf2f(unsigned short u) {
  union { unsigned int i; float f; } c; c.i = ((unsigned int)u) << 16; return c.f;
}
__device__ __forceinline__ float wred_sum(float x){
#pragma unroll
  for (int o = 32; o > 0; o >>= 1) x += __shfl_xor(x, o, 64);
  return x;
}

// async global->LDS, 16B per lane. LDS dest = wave-uniform base + lane*16.
__device__ __forceinline__ void gl_lds16(const unsigned short* g, unsigned short* l) {
  __builtin_amdgcn_global_load_lds(
      (const __attribute__((address_space(1))) unsigned int*)g,
      (__attribute__((address_space(3))) unsigned int*)l, 16, 0, 0);
}

// ================= merged prep kernel: 1D range dispatch ======================
// [0,5726)      cvt_atom   (fp32->bf16, 8/thread)
// [5726,9226)   cvt5       (weights + res_node fp32->bf16, 4/thread)
// [9226,9316)   mkmap      (padded-row -> source-row maps)
// [9316,9828)   wcomb      (Wc = Wk2/Wv2 @ Wo, fp32 tiles, bf16 out)
// [9828,10084)  bcomb      (bc = A@bo + b2, one wave per output)
__global__ __launch_bounds__(256) void prep(
    const float* __restrict__ atom_node, const float* __restrict__ res_node,
    const float* __restrict__ r2a_in_w,  const float* __restrict__ r2a_out_w,
    const float* __restrict__ r2a_out_b, const float* __restrict__ a2r_in_w,
    const float* __restrict__ a2r_in_b,  const float* __restrict__ a2r_out_w,
    unsigned short* __restrict__ w_r2a_in,  unsigned short* __restrict__ w_r2a_out,
    unsigned short* __restrict__ w_a2r_in,  unsigned short* __restrict__ w_a2r_out,
    unsigned short* __restrict__ res_bf,    unsigned short* __restrict__ atom_bf,
    int* __restrict__ mapA, int* __restrict__ mapR,
    unsigned short* __restrict__ wc_k, unsigned short* __restrict__ wc_v,
    float* __restrict__ bc_k, float* __restrict__ bc_v)
{
  __shared__ float sh[2304];        // wcomb tiles: As[32][36] | Bs[32][36]
  const int idx = blockIdx.x;
  const int tid = threadIdx.x;

  if (idx < 5726) {                 // ---- cvt_atom: NAD = 5726*2048 exactly
    const int i = (idx * 256 + tid) * 8;
    const float4 v0 = *reinterpret_cast<const float4*>(atom_node + i);
    const float4 v1 = *reinterpret_cast<const float4*>(atom_node + i + 4);
    short8 pk;
    pk[0] = (short)f2bf(v0.x); pk[1] = (short)f2bf(v0.y);
    pk[2] = (short)f2bf(v0.z); pk[3] = (short)f2bf(v0.w);
    pk[4] = (short)f2bf(v1.x); pk[5] = (short)f2bf(v1.y);
    pk[6] = (short)f2bf(v1.z); pk[7] = (short)f2bf(v1.w);
    *reinterpret_cast<short8*>(atom_bf + i) = pk;
  } else if (idx < 9226) {          // ---- cvt5: 768|256|768|256|1452 blocks
    const int r = idx - 5726;
    const float* s; unsigned short* d; int base;
    if (r < 768)       { s = r2a_in_w;  d = w_r2a_in;  base = r; }
    else if (r < 1024) { s = r2a_out_w; d = w_r2a_out; base = r - 768; }
    else if (r < 1792) { s = a2r_in_w;  d = w_a2r_in;  base = r - 1024; }
    else if (r < 2048) { s = a2r_out_w; d = w_a2r_out; base = r - 1792; }
    else               { s = res_node;  d = res_bf;    base = r - 2048; }
    const int i = (base * 256 + tid) * 4;
    const float4 v = *reinterpret_cast<const float4*>(s + i);
    ushort4v o = { f2bf(v.x), f2bf(v.y), f2bf(v.z), f2bf(v.w) };
    *reinterpret_cast<ushort4v*>(d + i) = o;
  } else if (idx < 9316) {          // ---- mkmap
    const int pm = (idx - 9226) * 256 + tid;
    if (pm < MPAD_A) {
      int b = 0;
#pragma unroll
      for (int i = 1; i < 16; ++i) if (pm >= c_apad[i]) b = i;
      const int rel = pm - c_apad[b];
      const int L = c_aoff[b+1] - c_aoff[b];
      mapA[pm] = c_aoff[b] + min(rel, L - 1);
    }
    if (pm < MPAD_R) {
      int b = 0;
#pragma unroll
      for (int i = 1; i < 16; ++i) if (pm >= c_rpad[i]) b = i;
      const int rel = pm - c_rpad[b];
      const int L = c_roff[b+1] - c_roff[b];
      mapR[pm] = c_roff[b] + min(rel, L - 1);
    }
  } else if (idx < 9828) {          // ---- wcomb: Wc = A @ Wo (bf16 out)
    const int widx = idx - 9316;
    const int z = widx >> 8, rem = widx & 255;
    const int m0 = (rem >> 4) * 32, n0 = (rem & 15) * 32;
    const float* A = a2r_in_w + (z ? 524288 : 262144);
    unsigned short* C = z ? wc_v : wc_k;
    float* As = sh;           // [32][36]
    float* Bs = sh + 1152;    // [32][36]
    const int ty = tid >> 4, tx = tid & 15;
    const int lr = tid >> 3, lc = (tid & 7) * 4;
    float acc[2][2] = {{0.f,0.f},{0.f,0.f}};
    for (int kb = 0; kb < 512; kb += 32) {
      const float4 av = *reinterpret_cast<const float4*>(A + (size_t)(m0+lr)*512 + kb + lc);
      As[lr*36+lc+0]=av.x; As[lr*36+lc+1]=av.y; As[lr*36+lc+2]=av.z; As[lr*36+lc+3]=av.w;
      const float4 bv = *reinterpret_cast<const float4*>(r2a_out_w + (size_t)(kb+lr)*512 + n0 + lc);
      Bs[lr*36+lc+0]=bv.x; Bs[lr*36+lc+1]=bv.y; Bs[lr*36+lc+2]=bv.z; Bs[lr*36+lc+3]=bv.w;
      __syncthreads();
#pragma unroll
      for (int k = 0; k < 32; ++k) {
        const float a0 = As[(ty*2)*36+k],  a1 = As[(ty*2+1)*36+k];
        const float b0 = Bs[k*36+tx*2],    b1 = Bs[k*36+tx*2+1];
        acc[0][0] = fmaf(a0,b0,acc[0][0]); acc[0][1] = fmaf(a0,b1,acc[0][1]);
        acc[1][0] = fmaf(a1,b0,acc[1][0]); acc[1][1] = fmaf(a1,b1,acc[1][1]);
      }
      __syncthreads();
    }
#pragma unroll
    for (int i = 0; i < 2; ++i)
#pragma unroll
      for (int j = 0; j < 2; ++j)
        C[(size_t)(m0+ty*2+i)*512 + n0 + tx*2+j] = f2bf(acc[i][j]);
  } else {                          // ---- bcomb: one wave per output n
    const int widx = idx - 9828;    // 0..255
    const int z = widx >> 7, blk = widx & 127;
    const int w = tid >> 6, lane = tid & 63;
    const int n = blk * 4 + w;
    const float* A  = a2r_in_w + (z ? 524288 : 262144) + (size_t)n * 512;
    const float* b2 = a2r_in_b + (z ? 1024 : 512);
    const float4 w0 = *reinterpret_cast<const float4*>(A + lane*8);
    const float4 w1 = *reinterpret_cast<const float4*>(A + lane*8 + 4);
    const float4 o0 = *reinterpret_cast<const float4*>(r2a_out_b + lane*8);
    const float4 o1 = *reinterpret_cast<const float4*>(r2a_out_b + lane*8 + 4);
    float s = w0.x*o0.x + w0.y*o0.y + w0.z*o0.z + w0.w*o0.w
            + w1.x*o1.x + w1.y*o1.y + w1.z*o1.z + w1.w*o1.w;
    s = wred_sum(s);
    if (lane == 0) (z ? bc_v : bc_k)[n] = s + b2[n];
  }
}

// ============ Multi-segment MFMA GEMM (counted-vmcnt, X depth-2 pipeline) =====
struct GSeg {
  const void* X; const unsigned short* W; const float* bias;
  unsigned short* Y; const int* map;
  int M; int ldY; int mtiles; int flags;   // flags: 2=transposed store, 4=remap
};
struct GSeg4 { GSeg s[4]; };

__global__ __launch_bounds__(256) void gemm_multi(GSeg4 P, int mtpx)
{
  __shared__ unsigned short SMEM[40960];   // X0|X1|X2|W0|W1 (80KB)
  unsigned short* const Xb0 = SMEM;
  unsigned short* const Xb1 = SMEM + 8192;
  unsigned short* const Xb2 = SMEM + 16384;
  unsigned short* const Wb0 = SMEM + 24576;
  unsigned short* const Wb1 = SMEM + 32768;
  const GSeg sg = P.s[blockIdx.y];
  const int xcd = blockIdx.x & 7, g = blockIdx.x >> 3;
  const int mt = xcd + 8 * (g % mtpx);
  const int nt = g / mtpx;
  if (mt >= sg.mtiles) return;
  const int m0 = mt * 128, n0 = nt * 128;
  const int OUTT = sg.flags & 2, REMAP = sg.flags & 4;
  const int tid = threadIdx.x, lane = tid & 63, w = tid >> 6;
  const int la = lane & 15, lg = lane >> 4;
  const int wm = (w & 1) * 64, wn = (w >> 1) * 64;
  const int w64 = w * 64;
  const unsigned short* Xg = (const unsigned short*)sg.X;

  f32x4 acc[4][4];
#pragma unroll
  for (int i = 0; i < 4; ++i)
#pragma unroll
    for (int j = 0; j < 4; ++j) acc[i][j] = (f32x4){0.f,0.f,0.f,0.f};

  int elA[4][2], elB[4][2];
#pragma unroll
  for (int i = 0; i < 4; ++i)
#pragma unroll
    for (int kc = 0; kc < 2; ++kc) {
      { const int r = wm + i*16 + la;
        elA[i][kc] = r*64 + ((kc*32 + lg*8) ^ ((r & 7) << 3)); }
      { const int r = wn + i*16 + la;
        elB[i][kc] = r*64 + ((kc*32 + lg*8) ^ ((r & 7) << 3)); }
    }

  int srow[4];
#pragma unroll
  for (int p = 0; p < 4; ++p) {
    const int slot = p*256 + tid;
    const int rg = min(m0 + (slot >> 3), sg.M - 1);
    srow[p] = REMAP ? sg.map[rg] : rg;
  }
  int scg[4], srw[4];
#pragma unroll
  for (int p = 0; p < 4; ++p) {
    const int slot = p*256 + tid;
    srw[p] = slot >> 3;
    scg[p] = ((slot & 7) ^ (srw[p] & 7)) << 3;   // swizzled GLOBAL col; LDS linear
  }

#define STAGE_W(DST, kb_)                                                       \
  _Pragma("unroll")                                                             \
  for (int p = 0; p < 4; ++p)                                                   \
    gl_lds16(sg.W + (size_t)(n0 + srw[p]) * DD + (kb_) + scg[p],                \
             &(DST)[(p*256 + w64) * 8]);

#define STAGE_X(DST, kb_)                                                       \
  _Pragma("unroll")                                                             \
  for (int p = 0; p < 4; ++p)                                                   \
    gl_lds16(Xg + (size_t)srow[p] * DD + (kb_) + scg[p],                        \
             &(DST)[(p*256 + w64) * 8]);

#define COMPUTE(XB, WB)                                                         \
  {                                                                             \
    short8 af[4][2], bfm[4][2];                                                 \
    _Pragma("unroll")                                                           \
    for (int i = 0; i < 4; ++i)                                                 \
      _Pragma("unroll")                                                         \
      for (int kc = 0; kc < 2; ++kc) {                                          \
        af[i][kc]  = *reinterpret_cast<const short8*>(&(XB)[elA[i][kc]]);       \
        bfm[i][kc] = *reinterpret_cast<const short8*>(&(WB)[elB[i][kc]]);       \
      }                                                                         \
    _Pragma("unroll")                                                           \
    for (int kc = 0; kc < 2; ++kc)                                              \
      _Pragma("unroll")                                                         \
      for (int i = 0; i < 4; ++i)                                               \
        _Pragma("unroll")                                                       \
        for (int j = 0; j < 4; ++j)                                             \
          acc[i][j] = __builtin_amdgcn_mfma_f32_16x16x32_bf16(af[i][kc], bfm[j][kc], acc[i][j], 0, 0, 0); \
  }

  STAGE_W(Wb0, 0);
  STAGE_X(Xb0, 0);
  STAGE_X(Xb1, 64);

#pragma unroll
  for (int k = 0; k < 8; ++k) {
    __builtin_amdgcn_s_barrier();
    asm volatile("" ::: "memory");
    if (k + 1 < 8) {
      if (((k+1) & 1) == 0) { STAGE_W(Wb0, (k+1)*64); } else { STAGE_W(Wb1, (k+1)*64); }
    }
    if (k + 2 < 8) {
      if (((k+2) % 3) == 0) { STAGE_X(Xb0, (k+2)*64); }
      else if (((k+2) % 3) == 1) { STAGE_X(Xb1, (k+2)*64); }
      else { STAGE_X(Xb2, (k+2)*64); }
    }
    if (k < 6)       { asm volatile("s_waitcnt vmcnt(12)" ::: "memory"); }
    else if (k == 6) { asm volatile("s_waitcnt vmcnt(8)" ::: "memory"); }
    else             { asm volatile("s_waitcnt vmcnt(0)" ::: "memory"); }
    __builtin_amdgcn_s_barrier();
    asm volatile("" ::: "memory");
    __builtin_amdgcn_sched_barrier(0);
    if ((k % 3) == 0)      { if ((k & 1) == 0) COMPUTE(Xb0, Wb0) else COMPUTE(Xb0, Wb1) }
    else if ((k % 3) == 1) { if ((k & 1) == 0) COMPUTE(Xb1, Wb0) else COMPUTE(Xb1, Wb1) }
    else                   { if ((k & 1) == 0) COMPUTE(Xb2, Wb0) else COMPUTE(Xb2, Wb1) }
  }

#undef STAGE_W
#undef STAGE_X
#undef COMPUTE

  __syncthreads();
  unsigned short* Cs = SMEM;
  if (!OUTT) {
#pragma unroll
    for (int j = 0; j < 4; ++j) {
      const int n = wn + j*16 + la;
      const float bj = sg.bias[n0 + n];
#pragma unroll
      for (int i = 0; i < 4; ++i) {
        const int mb = wm + i*16 + lg*4;
#pragma unroll
        for (int r = 0; r < 4; ++r) {
          const int m = mb + r;
          Cs[m*128 + (((n >> 3) ^ (m & 7)) << 3) + (n & 7)] = f2bf(acc[i][j][r] + bj);
        }
      }
    }
    __syncthreads();
#pragma unroll
    for (int p = 0; p < 8; ++p) {
      const int sid = p*256 + tid;
      const int row = sid >> 4, s = sid & 15;
      if (m0 + row < sg.M) {
        const short8 v = *reinterpret_cast<const short8*>(&Cs[row*128 + ((s ^ (row & 7)) << 3)]);
        *reinterpret_cast<short8*>(sg.Y + (size_t)(m0 + row)*sg.ldY + n0 + s*8) = v;
      }
    }
  } else {
#pragma unroll
    for (int j = 0; j < 4; ++j) {
      const int n = wn + j*16 + la;
      const float bj = sg.bias[n0 + n];
#pragma unroll
      for (int i = 0; i < 4; ++i) {
        const int mb = wm + i*16 + lg*4;
#pragma unroll
        for (int r = 0; r < 4; ++r) {
          const int m = mb + r;
          Cs[n*128 + (((m >> 3) ^ (n & 7)) << 3) + (m & 7)] = f2bf(acc[i][j][r] + bj);
        }
      }
    }
    __syncthreads();
#pragma unroll
    for (int p = 0; p < 8; ++p) {
      const int sid = p*256 + tid;
      const int row = sid >> 4, s = sid & 15;
      if (m0 + s*8 < sg.M) {
        const short8 v = *reinterpret_cast<const short8*>(&Cs[row*128 + ((s ^ (row & 7)) << 3)]);
        *reinterpret_cast<short8*>(sg.Y + (size_t)(n0 + row)*sg.ldY + m0 + s*8) = v;
      }
    }
  }
}

// ====== attention STAGE/COMPUTE macros (shared by attn_v7 / attn_sk) ==========
#define ATT_STAGE(bi, kc_)                                                      \
  {                                                                             \
    const int kbase_ = (kc_) * 64;                                              \
    _Pragma("unroll")                                                           \
    for (int p = 0; p < 2; ++p) {                                               \
      const int slot = p*256 + tid;                                             \
      const int row = slot >> 3, cg = slot & 7;                                 \
      const int srow = min(kbase_ + row, padL - 1);                             \
      gl_lds16(Kb + (size_t)srow * DD + ((cg ^ (row & 7)) << 3),                \
               &Ks[bi][(p*256 + w*64) * 8]);                                    \
    }                                                                           \
    _Pragma("unroll")                                                           \
    for (int p = 0; p < 2; ++p) {                                               \
      const int slot = p*256 + tid;                                             \
      const int row = slot >> 3, cg = slot & 7;                                 \
      const int col = min(kbase_ + ((cg ^ (row & 7)) << 3), padL - 8);          \
      gl_lds16(VTb + (size_t)row * ldvt + col, &Vs[bi][(p*256 + w*64) * 8]);    \
    }                                                                           \
  }

#define ATT_COMPUTE(bi, kbase)                                                  \
  {                                                                             \
    f32x4 S[4];                                                                 \
    _Pragma("unroll")                                                           \
    for (int j = 0; j < 4; ++j) {                                               \
      const int row = j*16 + la;                                                \
      const short8 kf0 = *reinterpret_cast<const short8*>(                      \
          &Ks[bi][row*64 + ((lg*8) ^ ((row & 7) << 3))]);                       \
      const short8 kf1 = *reinterpret_cast<const short8*>(                      \
          &Ks[bi][row*64 + ((32 + lg*8) ^ ((row & 7) << 3))]);                  \
      f32x4 s = (f32x4){0.f,0.f,0.f,0.f};                                       \
      s = __builtin_amdgcn_mfma_f32_16x16x32_bf16(qf[0], kf0, s, 0, 0, 0);      \
      s = __builtin_amdgcn_mfma_f32_16x16x32_bf16(qf[1], kf1, s, 0, 0, 0);      \
      S[j] = s;                                                                 \
    }                                                                           \
    _Pragma("unroll")                                                           \
    for (int j = 0; j < 4; ++j) {                                               \
      const bool ok = (kbase + j*16 + la) < Lk;                                 \
      _Pragma("unroll")                                                         \
      for (int r = 0; r < 4; ++r) {                                             \
        const float p = ok ? __expf(S[j][r] * 0.125f) : 0.f;                    \
        S[j][r] = p;                                                            \
        lsum[r] += p;                                                           \
      }                                                                         \
    }                                                                           \
    _Pragma("unroll")                                                           \
    for (int r = 0; r < 4; ++r) {                                               \
      const int prow = lg*4 + r;                                                \
      _Pragma("unroll")                                                         \
      for (int j = 0; j < 4; ++j)                                               \
        Pl[w][prow*64 + ((j*16 + la) ^ ((prow & 7) << 3))] = f2bf(S[j][r]);     \
    }                                                                           \
    __builtin_amdgcn_wave_barrier();                                            \
    const short8 pf0 = *reinterpret_cast<const short8*>(                        \
        &Pl[w][la*64 + ((lg*8) ^ ((la & 7) << 3))]);                            \
    const short8 pf1 = *reinterpret_cast<const short8*>(                        \
        &Pl[w][la*64 + ((32 + lg*8) ^ ((la & 7) << 3))]);                       \
    _Pragma("unroll")                                                           \
    for (int j = 0; j < 4; ++j) {                                               \
      const int d = j*16 + la;                                                  \
      const short8 vf0 = *reinterpret_cast<const short8*>(                      \
          &Vs[bi][d*64 + ((lg*8) ^ ((d & 7) << 3))]);                           \
      const short8 vf1 = *reinterpret_cast<const short8*>(                      \
          &Vs[bi][d*64 + ((32 + lg*8) ^ ((d & 7) << 3))]);                      \
      acc[j] = __builtin_amdgcn_mfma_f32_16x16x32_bf16(pf0, vf0, acc[j], 0, 0, 0); \
      acc[j] = __builtin_amdgcn_mfma_f32_16x16x32_bf16(pf1, vf1, acc[j], 0, 0, 0); \
    }                                                                           \
  }

// ============== attn1: full attention, counted-vmcnt staging ==================
__global__ __launch_bounds__(256, 4) void attn_v7(const unsigned short* __restrict__ Q,
                                                  const unsigned short* __restrict__ K,
                                                  const unsigned short* __restrict__ VT,
                                                  unsigned short* __restrict__ O, int ldvt)
{
  __shared__ unsigned short Ks[2][64*64];
  __shared__ unsigned short Vs[2][64*64];
  __shared__ unsigned short Pl[4][16*64];
  const int b = blockIdx.x >> 3, h = blockIdx.x & 7;
  const int Lq = c_aoff[b+1]-c_aoff[b], Lk = c_roff[b+1]-c_roff[b];
  const int padL = c_rpad[b+1]-c_rpad[b];
  const int q0b = blockIdx.y * 64;
  if (q0b >= Lq) return;
  const int tid = threadIdx.x, w = tid >> 6, lane = tid & 63;
  const int la = lane & 15, lg = lane >> 4;
  const int q0 = q0b + w*16;
  const unsigned short* Qb  = Q  + (size_t)c_aoff[b]*DD + h*64;
  const unsigned short* Kb  = K  + (size_t)c_rpad[b]*DD + h*64;
  const unsigned short* VTb = VT + (size_t)(h*64)*ldvt + c_rpad[b];

  short8 qf[2];
  {
    const int qrow = min(q0 + la, Lq - 1);
    qf[0] = *reinterpret_cast<const short8*>(Qb + (size_t)qrow*DD + lg*8);
    qf[1] = *reinterpret_cast<const short8*>(Qb + (size_t)qrow*DD + 32 + lg*8);
  }

  f32x4 acc[4];
#pragma unroll
  for (int j = 0; j < 4; ++j) acc[j] = (f32x4){0.f,0.f,0.f,0.f};
  float lsum[4] = {0.f,0.f,0.f,0.f};

  const int nkc = (Lk + 63) >> 6;
  ATT_STAGE(0, 0);
  for (int kc = 0; kc < nkc; ++kc) {
    const int bi = kc & 1;
    __builtin_amdgcn_s_barrier();
    asm volatile("" ::: "memory");
    if (kc + 1 < nkc) {
      ATT_STAGE(bi ^ 1, kc + 1);
      asm volatile("s_waitcnt vmcnt(4)" ::: "memory");
    } else {
      asm volatile("s_waitcnt vmcnt(0)" ::: "memory");
    }
    __builtin_amdgcn_s_barrier();
    asm volatile("" ::: "memory");
    __builtin_amdgcn_sched_barrier(0);
    const int kbase = kc * 64;
    ATT_COMPUTE(bi, kbase);
  }

#pragma unroll
  for (int msk = 1; msk <= 8; msk <<= 1)
#pragma unroll
    for (int r = 0; r < 4; ++r) lsum[r] += __shfl_xor(lsum[r], msk, 64);

#pragma unroll
  for (int r = 0; r < 4; ++r) {
    const float inv = 1.f / lsum[r];
    const int prow = lg*4 + r;
#pragma unroll
    for (int j = 0; j < 4; ++j)
      Pl[w][prow*64 + ((j*16 + la) ^ ((prow & 7) << 3))] = f2bf(acc[j][r] * inv);
  }
  __builtin_amdgcn_wave_barrier();
#pragma unroll
  for (int p = 0; p < 2; ++p) {
    const int sid = p*64 + lane;
    const int row = sid >> 3, s = sid & 7;
    const int qrow = q0 + row;
    if (qrow < Lq) {
      const short8 v = *reinterpret_cast<const short8*>(
          &Pl[w][row*64 + ((s ^ (row & 7)) << 3)]);
      *reinterpret_cast<short8*>(O + (size_t)(c_aoff[b] + qrow)*DD + h*64 + s*8) = v;
    }
  }
}

// ============== attn2: split-K partial attention (q=res, k/v=atoms) ===========
__global__ __launch_bounds__(256, 4) void attn_sk(const unsigned short* __restrict__ Q,
                                                  const unsigned short* __restrict__ K,
                                                  const unsigned short* __restrict__ VT,
                                                  float* __restrict__ Pout)
{
  __shared__ unsigned short Ks[2][64*64];
  __shared__ unsigned short Vs[2][64*64];
  __shared__ unsigned short Pl[4][16*64];
  const int b = blockIdx.x >> 3, h = blockIdx.x & 7;
  const int qt = blockIdx.y, z = blockIdx.z;
  const int Lq = c_roff[b+1]-c_roff[b], Lk = c_aoff[b+1]-c_aoff[b];
  const int padL = c_apad[b+1]-c_apad[b];
  const int ldvt = MPAD_A;
  const int q0b = qt * 64;
  if (q0b >= Lq) return;
  const int tid = threadIdx.x, w = tid >> 6, lane = tid & 63;
  const int la = lane & 15, lg = lane >> 4;
  const int q0 = q0b + w*16;
  float* pp = Pout + ((size_t)(blockIdx.x*4 + qt)*4 + z) * 4160;

  const int nkc = (Lk + 63) >> 6;
  const int cps = (nkc + 3) >> 2;
  const int k0 = z * cps, k1 = min(k0 + cps, nkc);
  if (k0 >= k1) {
    for (int i = tid; i < 4160; i += 256) pp[i] = 0.f;
    return;
  }

  const unsigned short* Qb  = Q  + (size_t)c_roff[b]*DD + h*64;
  const unsigned short* Kb  = K  + (size_t)c_apad[b]*DD + h*64;
  const unsigned short* VTb = VT + (size_t)(h*64)*ldvt + c_apad[b];

  short8 qf[2];
  {
    const int qrow = min(q0 + la, Lq - 1);
    qf[0] = *reinterpret_cast<const short8*>(Qb + (size_t)qrow*DD + lg*8);
    qf[1] = *reinterpret_cast<const short8*>(Qb + (size_t)qrow*DD + 32 + lg*8);
  }

  f32x4 acc[4];
#pragma unroll
  for (int j = 0; j < 4; ++j) acc[j] = (f32x4){0.f,0.f,0.f,0.f};
  float lsum[4] = {0.f,0.f,0.f,0.f};

  ATT_STAGE(0, k0);
  for (int kc = k0; kc < k1; ++kc) {
    const int bi = (kc - k0) & 1;
    __builtin_amdgcn_s_barrier();
    asm volatile("" ::: "memory");
    if (kc + 1 < k1) {
      ATT_STAGE(bi ^ 1, kc + 1);
      asm volatile("s_waitcnt vmcnt(4)" ::: "memory");
    } else {
      asm volatile("s_waitcnt vmcnt(0)" ::: "memory");
    }
    __builtin_amdgcn_s_barrier();
    asm volatile("" ::: "memory");
    __builtin_amdgcn_sched_barrier(0);
    const int kbase = kc * 64;
    ATT_COMPUTE(bi, kbase);
  }

#pragma unroll
  for (int msk = 1; msk <= 8; msk <<= 1)
#pragma unroll
    for (int r = 0; r < 4; ++r) lsum[r] += __shfl_xor(lsum[r], msk, 64);

#pragma unroll
  for (int j = 0; j < 4; ++j)
#pragma unroll
    for (int r = 0; r < 4; ++r)
      pp[(size_t)(w*16 + lg*4 + r)*64 + j*16 + la] = acc[j][r];
  if (la == 0) {
#pragma unroll
    for (int r = 0; r < 4; ++r) pp[4096 + w*16 + lg*4 + r] = lsum[r];
  }
}

// ============== attn2 reduce: sum 4 splits, normalize, write O2 bf16 ==========
__global__ __launch_bounds__(256) void attn_red(const float* __restrict__ Pin,
                                                unsigned short* __restrict__ O)
{
  const int b = blockIdx.x >> 3;
  const int h = blockIdx.x & 7;
  const int qt = blockIdx.y;
  const int Lq = c_roff[b+1]-c_roff[b];
  const int q0b = qt * 64;
  if (q0b >= Lq) return;
  const int t = threadIdx.x;
  const int row = t >> 2, dg = (t & 3) * 16;
  if (q0b + row >= Lq) return;
  const float* base = Pin + ((size_t)(blockIdx.x*4 + qt)*4) * 4160;
  const float ls = base[4096 + row] + base[4160 + 4096 + row]
                 + base[2*4160 + 4096 + row] + base[3*4160 + 4096 + row];
  const float inv = 1.f / ls;
  unsigned short ov[16];
#pragma unroll
  for (int e = 0; e < 16; ++e) {
    const int idx = row*64 + dg + e;
    const float s = base[idx] + base[4160 + idx] + base[2*4160 + idx] + base[3*4160 + idx];
    ov[e] = f2bf(s * inv);
  }
  unsigned short* dst = O + (size_t)(c_roff[b] + q0b + row)*DD + h*64 + dg;
  *reinterpret_cast<short8*>(dst)     = *reinterpret_cast<short8*>(&ov[0]);
  *reinterpret_cast<short8*>(dst + 8) = *reinterpret_cast<short8*>(&ov[8]);
}

// -------- LayerNorm over bf16 upd + fp32 residual -> fp32 d_out --------
__global__ __launch_bounds__(256) void ln_res(const unsigned short* __restrict__ Ub,
    float* __restrict__ Yout,
    const float* __restrict__ atom_node, const float* __restrict__ res_node,
    const float* __restrict__ ag, const float* __restrict__ ab,
    const float* __restrict__ rg, const float* __restrict__ rb)
{
  const int row = blockIdx.x * 4 + (threadIdx.x >> 6);
  const int lane = threadIdx.x & 63;
  if (row >= NA_TOT + NR_TOT) return;
  const float* g; const float* bb; const float* resid;
  if (row < NA_TOT) { g = ag; bb = ab; resid = atom_node + (size_t)row * DD; }
  else { g = rg; bb = rb; resid = res_node + (size_t)(row - NA_TOT) * DD; }
  const short8 xb = *reinterpret_cast<const short8*>(Ub + (size_t)row*DD + lane*8);
  float xv[8];
#pragma unroll
  for (int i = 0; i < 8; ++i) xv[i] = bf2f((unsigned short)xb[i]);
  float s = 0.f;
#pragma unroll
  for (int i = 0; i < 8; ++i) s += xv[i];
  s = wred_sum(s);
  const float mean = s * (1.f/512.f);
  float vs = 0.f;
#pragma unroll
  for (int i = 0; i < 8; ++i) { const float d = xv[i] - mean; vs = fmaf(d, d, vs); }
  vs = wred_sum(vs) * (1.f/512.f);
  const float inv = rsqrtf(vs + 1e-5f);
  const float4 g0 = *reinterpret_cast<const float4*>(g + lane*8);
  const float4 g1 = *reinterpret_cast<const float4*>(g + lane*8 + 4);
  const float4 b0 = *reinterpret_cast<const float4*>(bb + lane*8);
  const float4 b1 = *reinterpret_cast<const float4*>(bb + lane*8 + 4);
  const float4 r0 = *reinterpret_cast<const float4*>(resid + lane*8);
  const float4 r1 = *reinterpret_cast<const float4*>(resid + lane*8 + 4);
  float4 o0, o1;
  o0.x = (xv[0]-mean)*inv*g0.x + b0.x + r0.x;
  o0.y = (xv[1]-mean)*inv*g0.y + b0.y + r0.y;
  o0.z = (xv[2]-mean)*inv*g0.z + b0.z + r0.z;
  o0.w = (xv[3]-mean)*inv*g0.w + b0.w + r0.w;
  o1.x = (xv[4]-mean)*inv*g1.x + b1.x + r1.x;
  o1.y = (xv[5]-mean)*inv*g1.y + b1.y + r1.y;
  o1.z = (xv[6]-mean)*inv*g1.z + b1.z + r1.z;
  o1.w = (xv[7]-mean)*inv*g1.w + b1.w + r1.w;
  float* y = Yout + (size_t)row * DD + lane*8;
  *reinterpret_cast<float4*>(y)     = o0;
  *reinterpret_cast<float4*>(y + 4) = o1;
}

extern "C" void kernel_launch(void* const* d_in, const int* in_sizes, int n_in,
                              void* d_out, int out_size, void* d_ws, size_t ws_size,
                              hipStream_t stream) {
  (void)in_sizes; (void)n_in; (void)out_size; (void)ws_size;
  const float* atom_node = (const float*)d_in[0];
  const float* res_node  = (const float*)d_in[1];
  const float* r2a_in_w  = (const float*)d_in[2];
  const float* r2a_in_b  = (const float*)d_in[3];
  const float* r2a_out_w = (const float*)d_in[4];
  const float* r2a_out_b = (const float*)d_in[5];
  const float* a2r_in_w  = (const float*)d_in[6];
  const float* a2r_in_b  = (const float*)d_in[7];
  const float* a2r_out_w = (const float*)d_in[8];
  const float* a2r_out_b = (const float*)d_in[9];
  const float* atom_ln_g = (const float*)d_in[10];
  const float* atom_ln_b = (const float*)d_in[11];
  const float* res_ln_g  = (const float*)d_in[12];
  const float* res_ln_b  = (const float*)d_in[13];

  float* out = (float*)d_out;
  unsigned short* wsb = (unsigned short*)d_ws;
  const size_t NAD = (size_t)NA_TOT * DD;
  const size_t NRD = (size_t)NR_TOT * DD;
  const size_t PAD = (size_t)MPAD_A * DD;
  const size_t PRD = (size_t)MPAD_R * DD;
  // ws layout (~151 MB of 256 MB):
  unsigned short* slab1  = wsb;                    // [PAD] Q1 -> K2
  unsigned short* slab2  = wsb + PAD;              // [PAD] atom_bf -> O1
  unsigned short* slab3  = wsb + 2*PAD;            // [PAD] V2T
  unsigned short* updb   = wsb + 3*PAD;            // [NAD+NRD]
  unsigned short* res_bf = updb + NAD + NRD;       // [NRD]
  unsigned short* K1     = res_bf + NRD;           // [PRD]
  unsigned short* V1T    = K1 + PRD;               // [PRD]
  unsigned short* Q2     = V1T + PRD;              // [NRD]
  unsigned short* O2     = Q2 + NRD;               // [NRD]
  unsigned short* wbf    = O2 + NRD;               // [2097152]
  unsigned short* w_r2a_in  = wbf;
  unsigned short* w_r2a_out = wbf +  786432;
  unsigned short* w_a2r_in  = wbf + 1048576;
  unsigned short* w_a2r_out = wbf + 1835008;
  int* mapA = (int*)(wbf + 2097152);               // [MPAD_A]
  int* mapR = mapA + MPAD_A;                       // [MPAD_R]
  unsigned short* wc_k = (unsigned short*)(mapR + MPAD_R);   // [262144]
  unsigned short* wc_v = wc_k + 262144;                      // [262144]
  float* bc_k = (float*)(wc_v + 262144);           // [512]
  float* bc_v = bc_k + 512;                        // [512]
  float* partials = (float*)(bc_v + 512);          // [512*4*4160 fp32]
  unsigned short* Q1      = slab1;
  unsigned short* atom_bf = slab2;
  unsigned short* O1      = slab2;
  unsigned short* K2      = slab1;
  unsigned short* V2T     = slab3;

  const dim3 blk(256);

  // ---- all prep in ONE launch (cvt_atom | cvt5 | mkmap | wcomb | bcomb)
  prep<<<dim3(10084), blk, 0, stream>>>(
      atom_node, res_node, r2a_in_w, r2a_out_w, r2a_out_b, a2r_in_w, a2r_in_b,
      a2r_out_w, w_r2a_in, w_r2a_out, w_a2r_in, w_a2r_out, res_bf, atom_bf,
      mapA, mapR, wc_k, wc_v, bc_k, bc_v);

  // ---- group A: Q1, K1, V1T, Q2 projections (one launch)
  {
    GSeg4 A;
    A.s[0] = { atom_bf, w_r2a_in,          r2a_in_b,        Q1,  nullptr, NA_TOT, 512,    179, 0 };
    A.s[1] = { res_bf,  w_r2a_in + 262144, r2a_in_b + 512,  K1,  mapR,    MPAD_R, 512,    24,  4 };
    A.s[2] = { res_bf,  w_r2a_in + 524288, r2a_in_b + 1024, V1T, mapR,    MPAD_R, MPAD_R, 24,  6 };
    A.s[3] = { res_bf,  w_a2r_in,          a2r_in_b,        Q2,  nullptr, NR_TOT, 512,    23,  0 };
    gemm_multi<<<dim3(736, 4), blk, 0, stream>>>(A, 23);
  }
  // ---- attention 1 (q=atoms, k/v=res)
  attn_v7<<<dim3(128, 32), blk, 0, stream>>>(Q1, K1, V1T, O1, MPAD_R);
  // ---- group B': updb, K2, V2T — all directly from O1 (combined weights)
  {
    GSeg4 B;
    B.s[0] = { O1, w_r2a_out, r2a_out_b, updb, nullptr, NA_TOT, 512,    179, 0 };
    B.s[1] = { O1, wc_k,      bc_k,      K2,   mapA,    MPAD_A, 512,    180, 4 };
    B.s[2] = { O1, wc_v,      bc_v,      V2T,  mapA,    MPAD_A, MPAD_A, 180, 6 };
    B.s[3] = B.s[0];
    gemm_multi<<<dim3(736, 3), blk, 0, stream>>>(B, 23);
  }
  // ---- attention 2: split-K partials + reduce
  attn_sk<<<dim3(128, 4, 4), blk, 0, stream>>>(Q2, K2, V2T, partials);
  attn_red<<<dim3(128, 4), blk, 0, stream>>>(partials, O2);
  // ---- out-proj 2
  {
    GSeg4 E;
    E.s[0] = { O2, w_a2r_out, a2r_out_b, updb + NAD, nullptr, NR_TOT, 512, 23, 0 };
    E.s[1] = E.s[0]; E.s[2] = E.s[0]; E.s[3] = E.s[0];
    gemm_multi<<<dim3(96, 1), blk, 0, stream>>>(E, 3);
  }
  // ---- LayerNorm + residual
  ln_res<<<dim3((NA_TOT + NR_TOT + 3) / 4), blk, 0, stream>>>(
      updb, out, atom_node, res_node, atom_ln_g, atom_ln_b, res_ln_g, res_ln_b);
}

// Round 16
// 205.187 us; speedup vs baseline: 1.1755x; 1.1724x over previous
//
#include <hip/hip_runtime.h>
#include <hip/hip_bf16.h>
#include <math.h>

#define DD 512
#define NA_TOT 22904
#define NR_TOT 2904
#define MPAD_A 22960
#define MPAD_R 2960

__constant__ int c_aoff[17] = {0,1024,2145,3363,4678,6090,7599,9205,10908,12708,
                               14605,16599,17666,18830,20091,21449,22904};
__constant__ int c_roff[17] = {0,128,293,495,734,882,1067,1289,1420,1588,
                               1793,2035,2186,2374,2599,2733,2904};
__constant__ int c_apad[17] = {0,1024,2152,3376,4696,6112,7624,9232,10936,12736,
                               14640,16640,17712,18880,20144,21504,22960};
__constant__ int c_rpad[17] = {0,128,296,504,744,896,1088,1312,1448,1616,
                               1824,2072,2224,2416,2648,2784,2960};

typedef __attribute__((ext_vector_type(8))) short short8;
typedef __attribute__((ext_vector_type(4))) float f32x4;
typedef __attribute__((ext_vector_type(4))) unsigned short ushort4v;

__device__ __forceinline__ unsigned short f2bf(float f) {
  __hip_bfloat16 h = __float2bfloat16(f);   // RNE
  return *reinterpret_cast<unsigned short*>(&h);
}
__device__ __forceinline__ float bf2f(unsigned short u) {
  union { unsigned int i; float f; } c; c.i = ((unsigned int)u) << 16; return c.f;
}
__device__ __forceinline__ float wred_sum(float x){
#pragma unroll
  for (int o = 32; o > 0; o >>= 1) x += __shfl_xor(x, o, 64);
  return x;
}

// async global->LDS, 16B per lane. LDS dest = wave-uniform base + lane*16.
__device__ __forceinline__ void gl_lds16(const unsigned short* g, unsigned short* l) {
  __builtin_amdgcn_global_load_lds(
      (const __attribute__((address_space(1))) unsigned int*)g,
      (__attribute__((address_space(3))) unsigned int*)l, 16, 0, 0);
}

// ================= merged prep kernel: 1D range dispatch ======================
// [0,5726)      cvt_atom   (fp32->bf16, 8/thread)
// [5726,9226)   cvt5       (weights + res_node fp32->bf16, 4/thread)
// [9226,9316)   mkmap
// [9316,9572)   transpose  Wo -> WoT (bf16), 32x32 LDS tiles
// [9572,9828)   bcomb      (bc = A@bo + b2, one wave per output)
__global__ __launch_bounds__(256) void prep(
    const float* __restrict__ atom_node, const float* __restrict__ res_node,
    const float* __restrict__ r2a_in_w,  const float* __restrict__ r2a_out_w,
    const float* __restrict__ r2a_out_b, const float* __restrict__ a2r_in_w,
    const float* __restrict__ a2r_in_b,  const float* __restrict__ a2r_out_w,
    unsigned short* __restrict__ w_r2a_in,  unsigned short* __restrict__ w_r2a_out,
    unsigned short* __restrict__ w_a2r_in,  unsigned short* __restrict__ w_a2r_out,
    unsigned short* __restrict__ res_bf,    unsigned short* __restrict__ atom_bf,
    int* __restrict__ mapA, int* __restrict__ mapR,
    unsigned short* __restrict__ woT,
    float* __restrict__ bc_k, float* __restrict__ bc_v)
{
  __shared__ float sh[1056];        // transpose tile: [32][33]
  const int idx = blockIdx.x;
  const int tid = threadIdx.x;

  if (idx < 5726) {                 // ---- cvt_atom: NAD = 5726*2048 exactly
    const int i = (idx * 256 + tid) * 8;
    const float4 v0 = *reinterpret_cast<const float4*>(atom_node + i);
    const float4 v1 = *reinterpret_cast<const float4*>(atom_node + i + 4);
    short8 pk;
    pk[0] = (short)f2bf(v0.x); pk[1] = (short)f2bf(v0.y);
    pk[2] = (short)f2bf(v0.z); pk[3] = (short)f2bf(v0.w);
    pk[4] = (short)f2bf(v1.x); pk[5] = (short)f2bf(v1.y);
    pk[6] = (short)f2bf(v1.z); pk[7] = (short)f2bf(v1.w);
    *reinterpret_cast<short8*>(atom_bf + i) = pk;
  } else if (idx < 9226) {          // ---- cvt5: 768|256|768|256|1452 blocks
    const int r = idx - 5726;
    const float* s; unsigned short* d; int base;
    if (r < 768)       { s = r2a_in_w;  d = w_r2a_in;  base = r; }
    else if (r < 1024) { s = r2a_out_w; d = w_r2a_out; base = r - 768; }
    else if (r < 1792) { s = a2r_in_w;  d = w_a2r_in;  base = r - 1024; }
    else if (r < 2048) { s = a2r_out_w; d = w_a2r_out; base = r - 1792; }
    else               { s = res_node;  d = res_bf;    base = r - 2048; }
    const int i = (base * 256 + tid) * 4;
    const float4 v = *reinterpret_cast<const float4*>(s + i);
    ushort4v o = { f2bf(v.x), f2bf(v.y), f2bf(v.z), f2bf(v.w) };
    *reinterpret_cast<ushort4v*>(d + i) = o;
  } else if (idx < 9316) {          // ---- mkmap
    const int pm = (idx - 9226) * 256 + tid;
    if (pm < MPAD_A) {
      int b = 0;
#pragma unroll
      for (int i = 1; i < 16; ++i) if (pm >= c_apad[i]) b = i;
      const int rel = pm - c_apad[b];
      const int L = c_aoff[b+1] - c_aoff[b];
      mapA[pm] = c_aoff[b] + min(rel, L - 1);
    }
    if (pm < MPAD_R) {
      int b = 0;
#pragma unroll
      for (int i = 1; i < 16; ++i) if (pm >= c_rpad[i]) b = i;
      const int rel = pm - c_rpad[b];
      const int L = c_roff[b+1] - c_roff[b];
      mapR[pm] = c_roff[b] + min(rel, L - 1);
    }
  } else if (idx < 9572) {          // ---- transpose: WoT[m][n] = Wo[n][m] (bf16)
    const int t = idx - 9316;       // 256 tiles of 32x32
    const int tr = t >> 4, tc = t & 15;
    const int r = tid >> 3, c4 = (tid & 7) * 4;
    const float4 v = *reinterpret_cast<const float4*>(
        r2a_out_w + (size_t)(tr*32 + r) * 512 + tc*32 + c4);
    sh[r*33 + c4 + 0] = v.x; sh[r*33 + c4 + 1] = v.y;
    sh[r*33 + c4 + 2] = v.z; sh[r*33 + c4 + 3] = v.w;
    __syncthreads();
    const int a = tid >> 3, b4 = (tid & 7) * 4;
    ushort4v o = { f2bf(sh[(b4+0)*33 + a]), f2bf(sh[(b4+1)*33 + a]),
                   f2bf(sh[(b4+2)*33 + a]), f2bf(sh[(b4+3)*33 + a]) };
    *reinterpret_cast<ushort4v*>(woT + (size_t)(tc*32 + a) * 512 + tr*32 + b4) = o;
  } else {                          // ---- bcomb: one wave per output n
    const int widx = idx - 9572;    // 0..255
    const int z = widx >> 7, blk = widx & 127;
    const int w = tid >> 6, lane = tid & 63;
    const int n = blk * 4 + w;
    const float* A  = a2r_in_w + (z ? 524288 : 262144) + (size_t)n * 512;
    const float* b2 = a2r_in_b + (z ? 1024 : 512);
    const float4 w0 = *reinterpret_cast<const float4*>(A + lane*8);
    const float4 w1 = *reinterpret_cast<const float4*>(A + lane*8 + 4);
    const float4 o0 = *reinterpret_cast<const float4*>(r2a_out_b + lane*8);
    const float4 o1 = *reinterpret_cast<const float4*>(r2a_out_b + lane*8 + 4);
    float s = w0.x*o0.x + w0.y*o0.y + w0.z*o0.z + w0.w*o0.w
            + w1.x*o1.x + w1.y*o1.y + w1.z*o1.z + w1.w*o1.w;
    s = wred_sum(s);
    if (lane == 0) (z ? bc_v : bc_k)[n] = s + b2[n];
  }
}

// ============ Multi-segment MFMA GEMM (counted-vmcnt, X depth-2 pipeline) =====
struct GSeg {
  const void* X; const unsigned short* W; const float* bias;
  unsigned short* Y; const int* map;
  int M; int ldY; int mtiles; int flags;   // 2=transposed store, 4=remap, 8=no bias
};
struct GSeg6 { GSeg s[6]; };

__global__ __launch_bounds__(256) void gemm_multi(GSeg6 P, int mtpx)
{
  __shared__ unsigned short SMEM[40960];   // X0|X1|X2|W0|W1 (80KB)
  unsigned short* const Xb0 = SMEM;
  unsigned short* const Xb1 = SMEM + 8192;
  unsigned short* const Xb2 = SMEM + 16384;
  unsigned short* const Wb0 = SMEM + 24576;
  unsigned short* const Wb1 = SMEM + 32768;
  const GSeg sg = P.s[blockIdx.y];
  const int xcd = blockIdx.x & 7, g = blockIdx.x >> 3;
  const int mt = xcd + 8 * (g % mtpx);
  const int nt = g / mtpx;
  if (mt >= sg.mtiles) return;
  const int m0 = mt * 128, n0 = nt * 128;
  const int OUTT = sg.flags & 2, REMAP = sg.flags & 4, NOBIAS = sg.flags & 8;
  const int tid = threadIdx.x, lane = tid & 63, w = tid >> 6;
  const int la = lane & 15, lg = lane >> 4;
  const int wm = (w & 1) * 64, wn = (w >> 1) * 64;
  const int w64 = w * 64;
  const unsigned short* Xg = (const unsigned short*)sg.X;

  f32x4 acc[4][4];
#pragma unroll
  for (int i = 0; i < 4; ++i)
#pragma unroll
    for (int j = 0; j < 4; ++j) acc[i][j] = (f32x4){0.f,0.f,0.f,0.f};

  int elA[4][2], elB[4][2];
#pragma unroll
  for (int i = 0; i < 4; ++i)
#pragma unroll
    for (int kc = 0; kc < 2; ++kc) {
      { const int r = wm + i*16 + la;
        elA[i][kc] = r*64 + ((kc*32 + lg*8) ^ ((r & 7) << 3)); }
      { const int r = wn + i*16 + la;
        elB[i][kc] = r*64 + ((kc*32 + lg*8) ^ ((r & 7) << 3)); }
    }

  int srow[4];
#pragma unroll
  for (int p = 0; p < 4; ++p) {
    const int slot = p*256 + tid;
    const int rg = min(m0 + (slot >> 3), sg.M - 1);
    srow[p] = REMAP ? sg.map[rg] : rg;
  }
  int scg[4], srw[4];
#pragma unroll
  for (int p = 0; p < 4; ++p) {
    const int slot = p*256 + tid;
    srw[p] = slot >> 3;
    scg[p] = ((slot & 7) ^ (srw[p] & 7)) << 3;   // swizzled GLOBAL col; LDS linear
  }

#define STAGE_W(DST, kb_)                                                       \
  _Pragma("unroll")                                                             \
  for (int p = 0; p < 4; ++p)                                                   \
    gl_lds16(sg.W + (size_t)(n0 + srw[p]) * DD + (kb_) + scg[p],                \
             &(DST)[(p*256 + w64) * 8]);

#define STAGE_X(DST, kb_)                                                       \
  _Pragma("unroll")                                                             \
  for (int p = 0; p < 4; ++p)                                                   \
    gl_lds16(Xg + (size_t)srow[p] * DD + (kb_) + scg[p],                        \
             &(DST)[(p*256 + w64) * 8]);

#define COMPUTE(XB, WB)                                                         \
  {                                                                             \
    short8 af[4][2], bfm[4][2];                                                 \
    _Pragma("unroll")                                                           \
    for (int i = 0; i < 4; ++i)                                                 \
      _Pragma("unroll")                                                         \
      for (int kc = 0; kc < 2; ++kc) {                                          \
        af[i][kc]  = *reinterpret_cast<const short8*>(&(XB)[elA[i][kc]]);       \
        bfm[i][kc] = *reinterpret_cast<const short8*>(&(WB)[elB[i][kc]]);       \
      }                                                                         \
    _Pragma("unroll")                                                           \
    for (int kc = 0; kc < 2; ++kc)                                              \
      _Pragma("unroll")                                                         \
      for (int i = 0; i < 4; ++i)                                               \
        _Pragma("unroll")                                                       \
        for (int j = 0; j < 4; ++j)                                             \
          acc[i][j] = __builtin_amdgcn_mfma_f32_16x16x32_bf16(af[i][kc], bfm[j][kc], acc[i][j], 0, 0, 0); \
  }

  STAGE_W(Wb0, 0);
  STAGE_X(Xb0, 0);
  STAGE_X(Xb1, 64);

#pragma unroll
  for (int k = 0; k < 8; ++k) {
    __builtin_amdgcn_s_barrier();
    asm volatile("" ::: "memory");
    if (k + 1 < 8) {
      if (((k+1) & 1) == 0) { STAGE_W(Wb0, (k+1)*64); } else { STAGE_W(Wb1, (k+1)*64); }
    }
    if (k + 2 < 8) {
      if (((k+2) % 3) == 0) { STAGE_X(Xb0, (k+2)*64); }
      else if (((k+2) % 3) == 1) { STAGE_X(Xb1, (k+2)*64); }
      else { STAGE_X(Xb2, (k+2)*64); }
    }
    if (k < 6)       { asm volatile("s_waitcnt vmcnt(12)" ::: "memory"); }
    else if (k == 6) { asm volatile("s_waitcnt vmcnt(8)" ::: "memory"); }
    else             { asm volatile("s_waitcnt vmcnt(0)" ::: "memory"); }
    __builtin_amdgcn_s_barrier();
    asm volatile("" ::: "memory");
    __builtin_amdgcn_sched_barrier(0);
    if ((k % 3) == 0)      { if ((k & 1) == 0) COMPUTE(Xb0, Wb0) else COMPUTE(Xb0, Wb1) }
    else if ((k % 3) == 1) { if ((k & 1) == 0) COMPUTE(Xb1, Wb0) else COMPUTE(Xb1, Wb1) }
    else                   { if ((k & 1) == 0) COMPUTE(Xb2, Wb0) else COMPUTE(Xb2, Wb1) }
  }

#undef STAGE_W
#undef STAGE_X
#undef COMPUTE

  __syncthreads();
  unsigned short* Cs = SMEM;
  if (!OUTT) {
#pragma unroll
    for (int j = 0; j < 4; ++j) {
      const int n = wn + j*16 + la;
      const float bj = NOBIAS ? 0.f : sg.bias[n0 + n];
#pragma unroll
      for (int i = 0; i < 4; ++i) {
        const int mb = wm + i*16 + lg*4;
#pragma unroll
        for (int r = 0; r < 4; ++r) {
          const int m = mb + r;
          Cs[m*128 + (((n >> 3) ^ (m & 7)) << 3) + (n & 7)] = f2bf(acc[i][j][r] + bj);
        }
      }
    }
    __syncthreads();
#pragma unroll
    for (int p = 0; p < 8; ++p) {
      const int sid = p*256 + tid;
      const int row = sid >> 4, s = sid & 15;
      if (m0 + row < sg.M) {
        const short8 v = *reinterpret_cast<const short8*>(&Cs[row*128 + ((s ^ (row & 7)) << 3)]);
        *reinterpret_cast<short8*>(sg.Y + (size_t)(m0 + row)*sg.ldY + n0 + s*8) = v;
      }
    }
  } else {
#pragma unroll
    for (int j = 0; j < 4; ++j) {
      const int n = wn + j*16 + la;
      const float bj = NOBIAS ? 0.f : sg.bias[n0 + n];
#pragma unroll
      for (int i = 0; i < 4; ++i) {
        const int mb = wm + i*16 + lg*4;
#pragma unroll
        for (int r = 0; r < 4; ++r) {
          const int m = mb + r;
          Cs[n*128 + (((m >> 3) ^ (n & 7)) << 3) + (m & 7)] = f2bf(acc[i][j][r] + bj);
        }
      }
    }
    __syncthreads();
#pragma unroll
    for (int p = 0; p < 8; ++p) {
      const int sid = p*256 + tid;
      const int row = sid >> 4, s = sid & 15;
      if (m0 + s*8 < sg.M) {
        const short8 v = *reinterpret_cast<const short8*>(&Cs[row*128 + ((s ^ (row & 7)) << 3)]);
        *reinterpret_cast<short8*>(sg.Y + (size_t)(n0 + row)*sg.ldY + m0 + s*8) = v;
      }
    }
  }
}

// ====== attention STAGE/COMPUTE macros (shared by attn_v7 / attn_sk) ==========
#define ATT_STAGE(bi, kc_)                                                      \
  {                                                                             \
    const int kbase_ = (kc_) * 64;                                              \
    _Pragma("unroll")                                                           \
    for (int p = 0; p < 2; ++p) {                                               \
      const int slot = p*256 + tid;                                             \
      const int row = slot >> 3, cg = slot & 7;                                 \
      const int srow = min(kbase_ + row, padL - 1);                             \
      gl_lds16(Kb + (size_t)srow * DD + ((cg ^ (row & 7)) << 3),                \
               &Ks[bi][(p*256 + w*64) * 8]);                                    \
    }                                                                           \
    _Pragma("unroll")                                                           \
    for (int p = 0; p < 2; ++p) {                                               \
      const int slot = p*256 + tid;                                             \
      const int row = slot >> 3, cg = slot & 7;                                 \
      const int col = min(kbase_ + ((cg ^ (row & 7)) << 3), padL - 8);          \
      gl_lds16(VTb + (size_t)row * ldvt + col, &Vs[bi][(p*256 + w*64) * 8]);    \
    }                                                                           \
  }

#define ATT_COMPUTE(bi, kbase)                                                  \
  {                                                                             \
    f32x4 S[4];                                                                 \
    _Pragma("unroll")                                                           \
    for (int j = 0; j < 4; ++j) {                                               \
      const int row = j*16 + la;                                                \
      const short8 kf0 = *reinterpret_cast<const short8*>(                      \
          &Ks[bi][row*64 + ((lg*8) ^ ((row & 7) << 3))]);                       \
      const short8 kf1 = *reinterpret_cast<const short8*>(                      \
          &Ks[bi][row*64 + ((32 + lg*8) ^ ((row & 7) << 3))]);                  \
      f32x4 s = (f32x4){0.f,0.f,0.f,0.f};                                       \
      s = __builtin_amdgcn_mfma_f32_16x16x32_bf16(qf[0], kf0, s, 0, 0, 0);      \
      s = __builtin_amdgcn_mfma_f32_16x16x32_bf16(qf[1], kf1, s, 0, 0, 0);      \
      S[j] = s;                                                                 \
    }                                                                           \
    _Pragma("unroll")                                                           \
    for (int j = 0; j < 4; ++j) {                                               \
      const bool ok = (kbase + j*16 + la) < Lk;                                 \
      _Pragma("unroll")                                                         \
      for (int r = 0; r < 4; ++r) {                                             \
        const float p = ok ? __expf(S[j][r] * 0.125f) : 0.f;                    \
        S[j][r] = p;                                                            \
        lsum[r] += p;                                                           \
      }                                                                         \
    }                                                                           \
    _Pragma("unroll")                                                           \
    for (int r = 0; r < 4; ++r) {                                               \
      const int prow = lg*4 + r;                                                \
      _Pragma("unroll")                                                         \
      for (int j = 0; j < 4; ++j)                                               \
        Pl[w][prow*64 + ((j*16 + la) ^ ((prow & 7) << 3))] = f2bf(S[j][r]);     \
    }                                                                           \
    __builtin_amdgcn_wave_barrier();                                            \
    const short8 pf0 = *reinterpret_cast<const short8*>(                        \
        &Pl[w][la*64 + ((lg*8) ^ ((la & 7) << 3))]);                            \
    const short8 pf1 = *reinterpret_cast<const short8*>(                        \
        &Pl[w][la*64 + ((32 + lg*8) ^ ((la & 7) << 3))]);                       \
    _Pragma("unroll")                                                           \
    for (int j = 0; j < 4; ++j) {                                               \
      const int d = j*16 + la;                                                  \
      const short8 vf0 = *reinterpret_cast<const short8*>(                      \
          &Vs[bi][d*64 + ((lg*8) ^ ((d & 7) << 3))]);                           \
      const short8 vf1 = *reinterpret_cast<const short8*>(                      \
          &Vs[bi][d*64 + ((32 + lg*8) ^ ((d & 7) << 3))]);                      \
      acc[j] = __builtin_amdgcn_mfma_f32_16x16x32_bf16(pf0, vf0, acc[j], 0, 0, 0); \
      acc[j] = __builtin_amdgcn_mfma_f32_16x16x32_bf16(pf1, vf1, acc[j], 0, 0, 0); \
    }                                                                           \
  }

// ============== attn1: full attention, counted-vmcnt staging ==================
__global__ __launch_bounds__(256, 4) void attn_v7(const unsigned short* __restrict__ Q,
                                                  const unsigned short* __restrict__ K,
                                                  const unsigned short* __restrict__ VT,
                                                  unsigned short* __restrict__ O, int ldvt)
{
  __shared__ unsigned short Ks[2][64*64];
  __shared__ unsigned short Vs[2][64*64];
  __shared__ unsigned short Pl[4][16*64];
  const int b = blockIdx.x >> 3, h = blockIdx.x & 7;
  const int Lq = c_aoff[b+1]-c_aoff[b], Lk = c_roff[b+1]-c_roff[b];
  const int padL = c_rpad[b+1]-c_rpad[b];
  const int q0b = blockIdx.y * 64;
  if (q0b >= Lq) return;
  const int tid = threadIdx.x, w = tid >> 6, lane = tid & 63;
  const int la = lane & 15, lg = lane >> 4;
  const int q0 = q0b + w*16;
  const unsigned short* Qb  = Q  + (size_t)c_aoff[b]*DD + h*64;
  const unsigned short* Kb  = K  + (size_t)c_rpad[b]*DD + h*64;
  const unsigned short* VTb = VT + (size_t)(h*64)*ldvt + c_rpad[b];

  short8 qf[2];
  {
    const int qrow = min(q0 + la, Lq - 1);
    qf[0] = *reinterpret_cast<const short8*>(Qb + (size_t)qrow*DD + lg*8);
    qf[1] = *reinterpret_cast<const short8*>(Qb + (size_t)qrow*DD + 32 + lg*8);
  }

  f32x4 acc[4];
#pragma unroll
  for (int j = 0; j < 4; ++j) acc[j] = (f32x4){0.f,0.f,0.f,0.f};
  float lsum[4] = {0.f,0.f,0.f,0.f};

  const int nkc = (Lk + 63) >> 6;
  ATT_STAGE(0, 0);
  for (int kc = 0; kc < nkc; ++kc) {
    const int bi = kc & 1;
    __builtin_amdgcn_s_barrier();
    asm volatile("" ::: "memory");
    if (kc + 1 < nkc) {
      ATT_STAGE(bi ^ 1, kc + 1);
      asm volatile("s_waitcnt vmcnt(4)" ::: "memory");
    } else {
      asm volatile("s_waitcnt vmcnt(0)" ::: "memory");
    }
    __builtin_amdgcn_s_barrier();
    asm volatile("" ::: "memory");
    __builtin_amdgcn_sched_barrier(0);
    const int kbase = kc * 64;
    ATT_COMPUTE(bi, kbase);
  }

#pragma unroll
  for (int msk = 1; msk <= 8; msk <<= 1)
#pragma unroll
    for (int r = 0; r < 4; ++r) lsum[r] += __shfl_xor(lsum[r], msk, 64);

#pragma unroll
  for (int r = 0; r < 4; ++r) {
    const float inv = 1.f / lsum[r];
    const int prow = lg*4 + r;
#pragma unroll
    for (int j = 0; j < 4; ++j)
      Pl[w][prow*64 + ((j*16 + la) ^ ((prow & 7) << 3))] = f2bf(acc[j][r] * inv);
  }
  __builtin_amdgcn_wave_barrier();
#pragma unroll
  for (int p = 0; p < 2; ++p) {
    const int sid = p*64 + lane;
    const int row = sid >> 3, s = sid & 7;
    const int qrow = q0 + row;
    if (qrow < Lq) {
      const short8 v = *reinterpret_cast<const short8*>(
          &Pl[w][row*64 + ((s ^ (row & 7)) << 3)]);
      *reinterpret_cast<short8*>(O + (size_t)(c_aoff[b] + qrow)*DD + h*64 + s*8) = v;
    }
  }
}

// ============== attn2: split-K partial attention (q=res, k/v=atoms) ===========
__global__ __launch_bounds__(256, 4) void attn_sk(const unsigned short* __restrict__ Q,
                                                  const unsigned short* __restrict__ K,
                                                  const unsigned short* __restrict__ VT,
                                                  float* __restrict__ Pout)
{
  __shared__ unsigned short Ks[2][64*64];
  __shared__ unsigned short Vs[2][64*64];
  __shared__ unsigned short Pl[4][16*64];
  const int b = blockIdx.x >> 3, h = blockIdx.x & 7;
  const int qt = blockIdx.y, z = blockIdx.z;
  const int Lq = c_roff[b+1]-c_roff[b], Lk = c_aoff[b+1]-c_aoff[b];
  const int padL = c_apad[b+1]-c_apad[b];
  const int ldvt = MPAD_A;
  const int q0b = qt * 64;
  if (q0b >= Lq) return;
  const int tid = threadIdx.x, w = tid >> 6, lane = tid & 63;
  const int la = lane & 15, lg = lane >> 4;
  const int q0 = q0b + w*16;
  float* pp = Pout + ((size_t)(blockIdx.x*4 + qt)*4 + z) * 4160;

  const int nkc = (Lk + 63) >> 6;
  const int cps = (nkc + 3) >> 2;
  const int k0 = z * cps, k1 = min(k0 + cps, nkc);
  if (k0 >= k1) {
    for (int i = tid; i < 4160; i += 256) pp[i] = 0.f;
    return;
  }

  const unsigned short* Qb  = Q  + (size_t)c_roff[b]*DD + h*64;
  const unsigned short* Kb  = K  + (size_t)c_apad[b]*DD + h*64;
  const unsigned short* VTb = VT + (size_t)(h*64)*ldvt + c_apad[b];

  short8 qf[2];
  {
    const int qrow = min(q0 + la, Lq - 1);
    qf[0] = *reinterpret_cast<const short8*>(Qb + (size_t)qrow*DD + lg*8);
    qf[1] = *reinterpret_cast<const short8*>(Qb + (size_t)qrow*DD + 32 + lg*8);
  }

  f32x4 acc[4];
#pragma unroll
  for (int j = 0; j < 4; ++j) acc[j] = (f32x4){0.f,0.f,0.f,0.f};
  float lsum[4] = {0.f,0.f,0.f,0.f};

  ATT_STAGE(0, k0);
  for (int kc = k0; kc < k1; ++kc) {
    const int bi = (kc - k0) & 1;
    __builtin_amdgcn_s_barrier();
    asm volatile("" ::: "memory");
    if (kc + 1 < k1) {
      ATT_STAGE(bi ^ 1, kc + 1);
      asm volatile("s_waitcnt vmcnt(4)" ::: "memory");
    } else {
      asm volatile("s_waitcnt vmcnt(0)" ::: "memory");
    }
    __builtin_amdgcn_s_barrier();
    asm volatile("" ::: "memory");
    __builtin_amdgcn_sched_barrier(0);
    const int kbase = kc * 64;
    ATT_COMPUTE(bi, kbase);
  }

#pragma unroll
  for (int msk = 1; msk <= 8; msk <<= 1)
#pragma unroll
    for (int r = 0; r < 4; ++r) lsum[r] += __shfl_xor(lsum[r], msk, 64);

#pragma unroll
  for (int j = 0; j < 4; ++j)
#pragma unroll
    for (int r = 0; r < 4; ++r)
      pp[(size_t)(w*16 + lg*4 + r)*64 + j*16 + la] = acc[j][r];
  if (la == 0) {
#pragma unroll
    for (int r = 0; r < 4; ++r) pp[4096 + w*16 + lg*4 + r] = lsum[r];
  }
}

// ============== attn2 reduce: sum 4 splits, normalize, write O2 bf16 ==========
__global__ __launch_bounds__(256) void attn_red(const float* __restrict__ Pin,
                                                unsigned short* __restrict__ O)
{
  const int b = blockIdx.x >> 3;
  const int h = blockIdx.x & 7;
  const int qt = blockIdx.y;
  const int Lq = c_roff[b+1]-c_roff[b];
  const int q0b = qt * 64;
  if (q0b >= Lq) return;
  const int t = threadIdx.x;
  const int row = t >> 2, dg = (t & 3) * 16;
  if (q0b + row >= Lq) return;
  const float* base = Pin + ((size_t)(blockIdx.x*4 + qt)*4) * 4160;
  const float ls = base[4096 + row] + base[4160 + 4096 + row]
                 + base[2*4160 + 4096 + row] + base[3*4160 + 4096 + row];
  const float inv = 1.f / ls;
  unsigned short ov[16];
#pragma unroll
  for (int e = 0; e < 16; ++e) {
    const int idx = row*64 + dg + e;
    const float s = base[idx] + base[4160 + idx] + base[2*4160 + idx] + base[3*4160 + idx];
    ov[e] = f2bf(s * inv);
  }
  unsigned short* dst = O + (size_t)(c_roff[b] + q0b + row)*DD + h*64 + dg;
  *reinterpret_cast<short8*>(dst)     = *reinterpret_cast<short8*>(&ov[0]);
  *reinterpret_cast<short8*>(dst + 8) = *reinterpret_cast<short8*>(&ov[8]);
}

// -------- LayerNorm over bf16 upd + fp32 residual -> fp32 d_out --------
__global__ __launch_bounds__(256) void ln_res(const unsigned short* __restrict__ Ub,
    float* __restrict__ Yout,
    const float* __restrict__ atom_node, const float* __restrict__ res_node,
    const float* __restrict__ ag, const float* __restrict__ ab,
    const float* __restrict__ rg, const float* __restrict__ rb)
{
  const int row = blockIdx.x * 4 + (threadIdx.x >> 6);
  const int lane = threadIdx.x & 63;
  if (row >= NA_TOT + NR_TOT) return;
  const float* g; const float* bb; const float* resid;
  if (row < NA_TOT) { g = ag; bb = ab; resid = atom_node + (size_t)row * DD; }
  else { g = rg; bb = rb; resid = res_node + (size_t)(row - NA_TOT) * DD; }
  const short8 xb = *reinterpret_cast<const short8*>(Ub + (size_t)row*DD + lane*8);
  float xv[8];
#pragma unroll
  for (int i = 0; i < 8; ++i) xv[i] = bf2f((unsigned short)xb[i]);
  float s = 0.f;
#pragma unroll
  for (int i = 0; i < 8; ++i) s += xv[i];
  s = wred_sum(s);
  const float mean = s * (1.f/512.f);
  float vs = 0.f;
#pragma unroll
  for (int i = 0; i < 8; ++i) { const float d = xv[i] - mean; vs = fmaf(d, d, vs); }
  vs = wred_sum(vs) * (1.f/512.f);
  const float inv = rsqrtf(vs + 1e-5f);
  const float4 g0 = *reinterpret_cast<const float4*>(g + lane*8);
  const float4 g1 = *reinterpret_cast<const float4*>(g + lane*8 + 4);
  const float4 b0 = *reinterpret_cast<const float4*>(bb + lane*8);
  const float4 b1 = *reinterpret_cast<const float4*>(bb + lane*8 + 4);
  const float4 r0 = *reinterpret_cast<const float4*>(resid + lane*8);
  const float4 r1 = *reinterpret_cast<const float4*>(resid + lane*8 + 4);
  float4 o0, o1;
  o0.x = (xv[0]-mean)*inv*g0.x + b0.x + r0.x;
  o0.y = (xv[1]-mean)*inv*g0.y + b0.y + r0.y;
  o0.z = (xv[2]-mean)*inv*g0.z + b0.z + r0.z;
  o0.w = (xv[3]-mean)*inv*g0.w + b0.w + r0.w;
  o1.x = (xv[4]-mean)*inv*g1.x + b1.x + r1.x;
  o1.y = (xv[5]-mean)*inv*g1.y + b1.y + r1.y;
  o1.z = (xv[6]-mean)*inv*g1.z + b1.z + r1.z;
  o1.w = (xv[7]-mean)*inv*g1.w + b1.w + r1.w;
  float* y = Yout + (size_t)row * DD + lane*8;
  *reinterpret_cast<float4*>(y)     = o0;
  *reinterpret_cast<float4*>(y + 4) = o1;
}

extern "C" void kernel_launch(void* const* d_in, const int* in_sizes, int n_in,
                              void* d_out, int out_size, void* d_ws, size_t ws_size,
                              hipStream_t stream) {
  (void)in_sizes; (void)n_in; (void)out_size; (void)ws_size;
  const float* atom_node = (const float*)d_in[0];
  const float* res_node  = (const float*)d_in[1];
  const float* r2a_in_w  = (const float*)d_in[2];
  const float* r2a_in_b  = (const float*)d_in[3];
  const float* r2a_out_w = (const float*)d_in[4];
  const float* r2a_out_b = (const float*)d_in[5];
  const float* a2r_in_w  = (const float*)d_in[6];
  const float* a2r_in_b  = (const float*)d_in[7];
  const float* a2r_out_w = (const float*)d_in[8];
  const float* a2r_out_b = (const float*)d_in[9];
  const float* atom_ln_g = (const float*)d_in[10];
  const float* atom_ln_b = (const float*)d_in[11];
  const float* res_ln_g  = (const float*)d_in[12];
  const float* res_ln_b  = (const float*)d_in[13];

  float* out = (float*)d_out;
  unsigned short* wsb = (unsigned short*)d_ws;
  const size_t NAD = (size_t)NA_TOT * DD;
  const size_t NRD = (size_t)NR_TOT * DD;
  const size_t PAD = (size_t)MPAD_A * DD;
  const size_t PRD = (size_t)MPAD_R * DD;
  // ws layout (~180 MB of 256 MB):
  unsigned short* slab1  = wsb;                    // [PAD] Q1 -> K2
  unsigned short* slab2  = wsb + PAD;              // [PAD] atom_bf -> O1
  unsigned short* slab3  = wsb + 2*PAD;            // [PAD] V2T
  unsigned short* updb   = wsb + 3*PAD;            // [NAD+NRD]
  unsigned short* res_bf = updb + NAD + NRD;       // [NRD]
  unsigned short* K1     = res_bf + NRD;           // [PRD]
  unsigned short* V1T    = K1 + PRD;               // [PRD]
  unsigned short* Q2     = V1T + PRD;              // [NRD]
  unsigned short* O2     = Q2 + NRD;               // [NRD]
  unsigned short* wbf    = O2 + NRD;               // [2097152]
  unsigned short* w_r2a_in  = wbf;
  unsigned short* w_r2a_out = wbf +  786432;
  unsigned short* w_a2r_in  = wbf + 1048576;
  unsigned short* w_a2r_out = wbf + 1835008;
  int* mapA = (int*)(wbf + 2097152);               // [MPAD_A]
  int* mapR = mapA + MPAD_A;                       // [MPAD_R]
  unsigned short* wc_k = (unsigned short*)(mapR + MPAD_R);   // [262144]
  unsigned short* wc_v = wc_k + 262144;                      // [262144]
  unsigned short* woT  = wc_v + 262144;                      // [262144]
  float* bc_k = (float*)(woT + 262144);            // [512]
  float* bc_v = bc_k + 512;                        // [512]
  float* partials = (float*)(bc_v + 512);          // [512*4*4160 fp32]
  unsigned short* Q1      = slab1;
  unsigned short* atom_bf = slab2;
  unsigned short* O1      = slab2;
  unsigned short* K2      = slab1;
  unsigned short* V2T     = slab3;

  const dim3 blk(256);

  // ---- prep: cvt_atom | cvt5 | mkmap | Wo-transpose | bcomb (one launch)
  prep<<<dim3(9828), blk, 0, stream>>>(
      atom_node, res_node, r2a_in_w, r2a_out_w, r2a_out_b, a2r_in_w, a2r_in_b,
      a2r_out_w, w_r2a_in, w_r2a_out, w_a2r_in, w_a2r_out, res_bf, atom_bf,
      mapA, mapR, woT, bc_k, bc_v);

  // ---- group A: Q1, K1, V1T, Q2 projections + the two Wc mini-GEMMs
  {
    GSeg6 A;
    A.s[0] = { atom_bf,            w_r2a_in,          r2a_in_b,        Q1,   nullptr, NA_TOT, 512,    179, 0 };
    A.s[1] = { res_bf,             w_r2a_in + 262144, r2a_in_b + 512,  K1,   mapR,    MPAD_R, 512,    24,  4 };
    A.s[2] = { res_bf,             w_r2a_in + 524288, r2a_in_b + 1024, V1T,  mapR,    MPAD_R, MPAD_R, 24,  6 };
    A.s[3] = { res_bf,             w_a2r_in,          a2r_in_b,        Q2,   nullptr, NR_TOT, 512,    23,  0 };
    A.s[4] = { w_a2r_in + 262144,  woT,               nullptr,         wc_k, nullptr, 512,    512,    4,   8 };
    A.s[5] = { w_a2r_in + 524288,  woT,               nullptr,         wc_v, nullptr, 512,    512,    4,   8 };
    gemm_multi<<<dim3(736, 6), blk, 0, stream>>>(A, 23);
  }
  // ---- attention 1 (q=atoms, k/v=res)
  attn_v7<<<dim3(128, 32), blk, 0, stream>>>(Q1, K1, V1T, O1, MPAD_R);
  // ---- group B': updb, K2, V2T — all directly from O1 (combined weights)
  {
    GSeg6 B;
    B.s[0] = { O1, w_r2a_out, r2a_out_b, updb, nullptr, NA_TOT, 512,    179, 0 };
    B.s[1] = { O1, wc_k,      bc_k,      K2,   mapA,    MPAD_A, 512,    180, 4 };
    B.s[2] = { O1, wc_v,      bc_v,      V2T,  mapA,    MPAD_A, MPAD_A, 180, 6 };
    B.s[3] = B.s[0]; B.s[4] = B.s[0]; B.s[5] = B.s[0];
    gemm_multi<<<dim3(736, 3), blk, 0, stream>>>(B, 23);
  }
  // ---- attention 2: split-K partials + reduce
  attn_sk<<<dim3(128, 4, 4), blk, 0, stream>>>(Q2, K2, V2T, partials);
  attn_red<<<dim3(128, 4), blk, 0, stream>>>(partials, O2);
  // ---- out-proj 2
  {
    GSeg6 E;
    E.s[0] = { O2, w_a2r_out, a2r_out_b, updb + NAD, nullptr, NR_TOT, 512, 23, 0 };
    E.s[1] = E.s[0]; E.s[2] = E.s[0]; E.s[3] = E.s[0]; E.s[4] = E.s[0]; E.s[5] = E.s[0];
    gemm_multi<<<dim3(96, 1), blk, 0, stream>>>(E, 3);
  }
  // ---- LayerNorm + residual
  ln_res<<<dim3((NA_TOT + NR_TOT + 3) / 4), blk, 0, stream>>>(
      updb, out, atom_node, res_node, atom_ln_g, atom_ln_b, res_ln_g, res_ln_b);
}